// Round 7
// baseline (623.489 us; speedup 1.0000x reference)
//
#include <hip/hip_runtime.h>
#include <math.h>

// Problem constants: B=2, H=W=32 (after expand), L=1024, out_dim=384, Di=768,
// K=4 directions, N=16 state, R=24, depth=2. fp32 in/out; bf16 MFMA GEMMs.

typedef __attribute__((ext_vector_type(8))) short s8v;   // 8 bf16 = 4 VGPRs
typedef __attribute__((ext_vector_type(4))) float f4v;

static __device__ __forceinline__ float sigmoidf_(float x) {
    return 1.f / (1.f + __expf(-x));
}
static __device__ __forceinline__ ushort f2bf(float x) {
    unsigned u = __float_as_uint(x);
    return (ushort)((u + 0x7fff + ((u >> 16) & 1)) >> 16);   // RNE
}
static __device__ __forceinline__ float bf2f(ushort u) {
    return __uint_as_float(((unsigned)u) << 16);
}

// Scan-order <-> spatial-position map. Involution for all k.
static __device__ __forceinline__ int scan_pos(int k, int l) {
    int m = (k & 2) ? (1023 - l) : l;
    return (k & 1) ? (((m & 31) << 5) | (m >> 5)) : m;
}

// ---------------- all weight conversions fp32->bf16 in ONE kernel ----------------
__global__ __launch_bounds__(256) void cvt_all_k(
    const float* __restrict__ pew, const float* __restrict__ lpw,
    const float* __restrict__ inw, const float* __restrict__ ow,
    const float* __restrict__ xpw, const float* __restrict__ dtw,
    ushort* __restrict__ wpe, ushort* __restrict__ wlp,
    ushort* __restrict__ winb, ushort* __restrict__ wob,
    ushort* __restrict__ wxpp, ushort* __restrict__ wdtp) {
    int g = blockIdx.x * 256 + threadIdx.x;
    if (g < 811008) {
        const float* s; ushort* d; int off;
        if (g < 294912)      { s = pew;  d = wpe;  off = g; }
        else if (g < 368640) { s = lpw;  d = wlp;  off = g - 294912; }
        else if (g < 663552) { s = inw;  d = winb; off = g - 368640; }
        else                 { s = ow;   d = wob;  off = g - 663552; }
        float4 v = ((const float4*)s)[off];
        ushort4 o = {f2bf(v.x), f2bf(v.y), f2bf(v.z), f2bf(v.w)};
        ((ushort4*)d)[off] = o;
    } else if (g < 909312) {
        int e = g - 811008;
        int blkb = e / 49152, rem = e % 49152;
        int n = rem / 192, q = rem % 192;
        int k = n >> 6, c = n & 63;
        ushort4 o = {0, 0, 0, 0};
        if (c < 56) {
            float4 v = *(const float4*)(xpw +
                ((size_t)((blkb * 4 + k) * 56 + c)) * 768 + q * 4);
            o = {f2bf(v.x), f2bf(v.y), f2bf(v.z), f2bf(v.w)};
        }
        ((ushort4*)wxpp)[e] = o;
    } else {
        int e = g - 909312;          // 49152 groups
        int rowk = e >> 3, q = e & 7;
        ushort4 o = {0, 0, 0, 0};
        if (q < 6) {
            float4 v = *(const float4*)(dtw + (size_t)rowk * 24 + q * 4);
            o = {f2bf(v.x), f2bf(v.y), f2bf(v.z), f2bf(v.w)};
        }
        ((ushort4*)wdtp)[e] = o;
    }
}

// ---------------- tiled transpose: x (B,768,256) -> (B*256,768) bf16 -------------
__global__ __launch_bounds__(256) void tr_x_k(const float* __restrict__ x,
                                              ushort* __restrict__ o) {
    __shared__ float tile[32][33];
    int b = blockIdx.z, c0 = blockIdx.y * 32, s0 = blockIdx.x * 32;
    int tx = threadIdx.x & 31, ty = threadIdx.x >> 5;
    for (int i = ty; i < 32; i += 8)
        tile[i][tx] = x[((size_t)(b * 768 + c0 + i)) * 256 + s0 + tx];
    __syncthreads();
    for (int i = ty; i < 32; i += 8)
        o[((size_t)(b * 256 + s0 + i)) * 768 + c0 + tx] = f2bf(tile[tx][i]);
}

// ---------------- merged: pe_ln (blocks 0..511) + tr_skip (blocks 512..1279) -----
__global__ __launch_bounds__(256) void peskip_k(const float* __restrict__ t1,
                                                const float* __restrict__ pnw,
                                                const float* __restrict__ pnb,
                                                const float* __restrict__ skip,
                                                ushort* __restrict__ cin) {
    __shared__ float tile[32][33];
    int bx = blockIdx.x;
    if (bx < 512) {
        int w = threadIdx.x >> 6, lane = threadIdx.x & 63;
        int row = bx * 4 + w;
        int b = row >> 10, p = row & 1023;
        int r = p >> 5, col = p & 31;
        int i = r >> 1, a = r & 1, j = col >> 1, b2 = col & 1;
        const float* src =
            t1 + ((size_t)(b * 256 + i * 16 + j)) * 1536 + (a * 2 + b2) * 384;
        float v[6], s1 = 0.f, s2 = 0.f;
#pragma unroll
        for (int q = 0; q < 6; ++q) {
            v[q] = src[lane + 64 * q];
            s1 += v[q]; s2 += v[q] * v[q];
        }
#pragma unroll
        for (int m = 1; m < 64; m <<= 1) {
            s1 += __shfl_xor(s1, m); s2 += __shfl_xor(s2, m);
        }
        float mean = s1 * (1.f / 384.f);
        float rstd = rsqrtf(s2 * (1.f / 384.f) - mean * mean + 1e-5f);
        ushort* o = cin + (size_t)row * 768;
#pragma unroll
        for (int q = 0; q < 6; ++q) {
            int c = lane + 64 * q;
            o[c] = f2bf((v[q] - mean) * rstd * pnw[c] + pnb[c]);
        }
    } else {
        int idx = bx - 512;                 // 768 blocks: b (2) x c0 (12) x s0 (32)
        int b = idx / 384, rem = idx % 384;
        int c0 = (rem / 32) * 32, s0 = (rem % 32) * 32;
        int tx = threadIdx.x & 31, ty = threadIdx.x >> 5;
        for (int i = ty; i < 32; i += 8)
            tile[i][tx] = skip[((size_t)(b * 384 + c0 + i)) * 1024 + s0 + tx];
        __syncthreads();
        for (int i = ty; i < 32; i += 8)
            cin[((size_t)(b * 1024 + s0 + i)) * 768 + 384 + c0 + tx] =
                f2bf(tile[tx][i]);
    }
}

// ---------------- tiled transpose: xh (B*1024,384) -> out (B,384,1024) fp32 ------
__global__ __launch_bounds__(256) void tr_out_k(const float* __restrict__ xh,
                                                float* __restrict__ out) {
    __shared__ float tile[32][33];
    int b = blockIdx.z, p0 = blockIdx.x * 32, c0 = blockIdx.y * 32;
    int tx = threadIdx.x & 31, ty = threadIdx.x >> 5;
    for (int i = ty; i < 32; i += 8)
        tile[i][tx] = xh[((size_t)(b * 1024 + p0 + i)) * 384 + c0 + tx];
    __syncthreads();
    for (int i = ty; i < 32; i += 8)
        out[((size_t)(b * 384 + c0 + i)) * 1024 + p0 + tx] = tile[tx][i];
}

// ---------------- bf16 NT MFMA GEMM, templated tile width, pipelined -------------
// BN=128: 4 waves 2x2, wave 64x64. BN=64: 4 waves stacked in M, wave 32x64.
// Double-buffered LDS; next tile's global loads issued before MFMAs (vmcnt wait
// lands after). mode 0: Cf=acc(+bias)(+res). mode 1 (dt-proj, z=k): scan-order
// row-scatter Cb[(k*2+b)*1024 + scan_pos(k,p)][col] = bf16(softplus(acc+bias)).
// mode 2 (xproj): dtrb bf16 + dblBC fp32 scan-order scatter.
template <int BN>
__global__ __launch_bounds__(256) void gemm_t(const ushort* __restrict__ A,
                                              const ushort* __restrict__ B,
                                              const float* __restrict__ bias,
                                              const float* __restrict__ res,
                                              float* __restrict__ Cf,
                                              ushort* __restrict__ Cb,
                                              float* __restrict__ dblBC,
                                              ushort* __restrict__ dtrb,
                                              int M, int N, int K,
                                              long sAz, long sBz, long sBiz,
                                              long sCz, int mode) {
    constexpr int MI = (BN == 128) ? 4 : 2;
    __shared__ ushort Als[2][128][40];   // 80 B rows: 20-bank stride, 2-way free
    __shared__ ushort Bls[2][BN][40];
    A += (size_t)blockIdx.z * sAz;
    B += (size_t)blockIdx.z * sBz;
    if (Cf) Cf += (size_t)blockIdx.z * sCz;
    if (bias) bias += (size_t)blockIdx.z * sBiz;
    int t = threadIdx.x;
    int bm = blockIdx.y * 128, bn = blockIdx.x * BN;
    int lane = t & 63, w = t >> 6;
    int wm = (BN == 128) ? (w & 1) * 64 : w * 32;
    int wn = (BN == 128) ? (w >> 1) * 64 : 0;
    int r16 = lane & 15, quad = lane >> 4;
    int srow = t >> 1, shalf = t & 1;
    int brow = (BN == 128) ? (t >> 1) : (t >> 2);
    int bq   = (BN == 128) ? (t & 1) * 16 : (t & 3) * 8;
    f4v acc[MI][4] = {};
    const ushort* Ag = A + (size_t)(bm + srow) * K + shalf * 16;
    const ushort* Bg = B + (size_t)(bn + brow) * K + bq;
    int nt = K >> 5;
    uint4 a0, a1, b0, b1;
    a0 = *(const uint4*)(Ag);
    a1 = *(const uint4*)(Ag + 8);
    b0 = *(const uint4*)(Bg);
    if (BN == 128) b1 = *(const uint4*)(Bg + 8);
    *(uint4*)&Als[0][srow][shalf * 16] = a0;
    *(uint4*)&Als[0][srow][shalf * 16 + 8] = a1;
    *(uint4*)&Bls[0][brow][bq] = b0;
    if (BN == 128) *(uint4*)&Bls[0][brow][bq + 8] = b1;
    for (int it = 0; it < nt; ++it) {
        int buf = it & 1;
        __syncthreads();                  // LDS[buf] ready; prev reads of buf^1 done
        if (it + 1 < nt) {                // issue next tile's loads
            int k0 = (it + 1) << 5;
            a0 = *(const uint4*)(Ag + k0);
            a1 = *(const uint4*)(Ag + k0 + 8);
            b0 = *(const uint4*)(Bg + k0);
            if (BN == 128) b1 = *(const uint4*)(Bg + k0 + 8);
        }
        s8v af[MI], bfr[4];
#pragma unroll
        for (int i = 0; i < MI; ++i)
            af[i] = *(const s8v*)&Als[buf][wm + i * 16 + r16][quad * 8];
#pragma unroll
        for (int j = 0; j < 4; ++j)
            bfr[j] = *(const s8v*)&Bls[buf][wn + j * 16 + r16][quad * 8];
#pragma unroll
        for (int i = 0; i < MI; ++i)
#pragma unroll
            for (int j = 0; j < 4; ++j)
                acc[i][j] = __builtin_amdgcn_mfma_f32_16x16x32_bf16(
                    af[i], bfr[j], acc[i][j], 0, 0, 0);
        if (it + 1 < nt) {                // vmcnt wait lands here, after MFMAs
            *(uint4*)&Als[buf ^ 1][srow][shalf * 16] = a0;
            *(uint4*)&Als[buf ^ 1][srow][shalf * 16 + 8] = a1;
            *(uint4*)&Bls[buf ^ 1][brow][bq] = b0;
            if (BN == 128) *(uint4*)&Bls[buf ^ 1][brow][bq + 8] = b1;
        }
    }
    // D mapping: col=lane&15, row=quad*4+reg (m89-verified)
#pragma unroll
    for (int i = 0; i < MI; ++i) {
        int row0 = bm + wm + i * 16 + quad * 4;
#pragma unroll
        for (int j = 0; j < 4; ++j) {
            int col = bn + wn + j * 16 + r16;
            float bv = bias ? bias[col] : 0.f;
#pragma unroll
            for (int r = 0; r < 4; ++r) {
                int row = row0 + r;
                float v = acc[i][j][r] + bv;
                if (mode == 0) {
                    if (res) v += res[(size_t)row * N + col];
                    Cf[(size_t)row * N + col] = v;
                } else if (mode == 1) {
                    v = (v > 20.f) ? v : log1pf(__expf(v));
                    int k = blockIdx.z, b = row >> 10, p = row & 1023;
                    int l = scan_pos(k, p);
                    Cb[((size_t)((k * 2 + b) * 1024 + l)) * 768 + col] = f2bf(v);
                } else {
                    int k = col >> 6, c = col & 63;
                    int b = row >> 10, p = row & 1023;
                    if (c < 32)
                        dtrb[((size_t)k * 2048 + row) * 32 + c] =
                            f2bf((c < 24) ? v : 0.f);
                    if (c >= 24 && c < 56) {
                        int l = scan_pos(k, p);
                        dblBC[(((size_t)(b * 4 + k)) * 1024 + l) * 32 + (c - 24)] = v;
                    }
                }
            }
        }
    }
}

// ---------------- row LayerNorm over 384 cols -> bf16 (wave/row) ----------------
__global__ __launch_bounds__(256) void ln_rows_384(const float* __restrict__ in,
                                                   const float* __restrict__ wgt,
                                                   const float* __restrict__ bb,
                                                   ushort* __restrict__ out) {
    int w = threadIdx.x >> 6, lane = threadIdx.x & 63;
    int row = blockIdx.x * 4 + w;      // grid 512
    const float* x = in + (size_t)row * 384;
    float v[6], s1 = 0.f, s2 = 0.f;
#pragma unroll
    for (int q = 0; q < 6; ++q) {
        v[q] = x[lane + 64 * q];
        s1 += v[q]; s2 += v[q] * v[q];
    }
#pragma unroll
    for (int m = 1; m < 64; m <<= 1) {
        s1 += __shfl_xor(s1, m); s2 += __shfl_xor(s2, m);
    }
    float mean = s1 * (1.f / 384.f);
    float rstd = rsqrtf(s2 * (1.f / 384.f) - mean * mean + 1e-5f);
#pragma unroll
    for (int q = 0; q < 6; ++q) {
        int c = lane + 64 * q;
        out[(size_t)row * 384 + c] = f2bf((v[q] - mean) * rstd * wgt[c] + bb[c]);
    }
}

// ------- depthwise 3x3 conv + bias + SiLU -> xcb (spatial) + xcwh (transposed) ---
__global__ __launch_bounds__(256) void conv_silu_k(const float* __restrict__ xz,
                                                   const float* __restrict__ cw,
                                                   const float* __restrict__ cb,
                                                   ushort* __restrict__ xcb,
                                                   ushort* __restrict__ xcwh) {
    int row = blockIdx.x;
    int b = row >> 10, p = row & 1023;
    int r = p >> 5, col = p & 31;
    int mwh = ((p & 31) << 5) | (p >> 5);
    for (int d = threadIdx.x; d < 768; d += 256) {
        float acc = cb[d];
#pragma unroll
        for (int dy = 0; dy < 3; ++dy) {
            int rr = r + dy - 1;
            if ((unsigned)rr > 31u) continue;
#pragma unroll
            for (int dx = 0; dx < 3; ++dx) {
                int cc = col + dx - 1;
                if ((unsigned)cc > 31u) continue;
                acc += cw[d * 9 + dy * 3 + dx] *
                       xz[((size_t)(b * 1024 + rr * 32 + cc)) * 1536 + d];
            }
        }
        float o = acc * sigmoidf_(acc);
        ushort ob = f2bf(o);
        xcb[(size_t)row * 768 + d] = ob;
        xcwh[((size_t)(b * 1024 + mwh)) * 768 + d] = ob;
    }
}

// ======== selective scan: fully sequential IO (scan-order layouts) ========
// dtscan bf16 [(k*2+b)*1024+l][768]; u: xcb (k even) / xcwh (k odd), row l or
// 1023-l (k>=2); dblBC fp32 scan-order; y4b written in scan order.
// Chunks: 32 x 32 steps. Pg/Hg/H0g: [(kb*32+ch)*12288 + d*16 + n].

__global__ __launch_bounds__(64) void scan_p1(const ushort* __restrict__ dtscan,
                                              const float* __restrict__ dblBC,
                                              const ushort* __restrict__ xcb,
                                              const ushort* __restrict__ xcwh,
                                              const float* __restrict__ alog,
                                              float* __restrict__ Pg,
                                              float* __restrict__ Hg) {
    __shared__ float sB[32][16];
    int lane = threadIdx.x;
    int d0 = blockIdx.x * 64, ch = blockIdx.y, kb = blockIdx.z;
    int k = kb & 3, b = kb >> 2;
    int d = d0 + lane;
    float A2[16];
    {
        const float4* ap = (const float4*)(alog + ((size_t)(k * 768 + d)) * 16);
#pragma unroll
        for (int q = 0; q < 4; ++q) {
            float4 v = ap[q];
            A2[4 * q + 0] = -__expf(v.x) * 1.44269504f;
            A2[4 * q + 1] = -__expf(v.y) * 1.44269504f;
            A2[4 * q + 2] = -__expf(v.z) * 1.44269504f;
            A2[4 * q + 3] = -__expf(v.w) * 1.44269504f;
        }
    }
    int l0 = ch * 32;
    const ushort* dts = dtscan + ((size_t)((k * 2 + b) * 1024 + l0)) * 768 + d;
    const ushort* ub = ((k & 1) ? xcwh : xcb) + (size_t)b * 786432 + d;
    const float* bcp = dblBC + (size_t)kb * 1024 * 32;
    float rdt[32], ru[32], rB[8];
#pragma unroll
    for (int i = 0; i < 32; ++i) rdt[i] = bf2f(dts[(size_t)i * 768]);
    if (k & 2) {
#pragma unroll
        for (int i = 0; i < 32; ++i)
            ru[i] = bf2f(ub[(size_t)(1023 - (l0 + i)) * 768]);
    } else {
#pragma unroll
        for (int i = 0; i < 32; ++i) ru[i] = bf2f(ub[(size_t)(l0 + i) * 768]);
    }
    int bi = lane >> 4, bn_ = lane & 15;
#pragma unroll
    for (int j = 0; j < 8; ++j)
        rB[j] = bcp[(size_t)(l0 + bi + 4 * j) * 32 + bn_];
#pragma unroll
    for (int j = 0; j < 8; ++j) sB[bi + 4 * j][bn_] = rB[j];
    __syncthreads();
    float h[16], P[16];
#pragma unroll
    for (int n = 0; n < 16; ++n) { h[n] = 0.f; P[n] = 1.f; }
#pragma unroll 4
    for (int i = 0; i < 32; ++i) {
        float dtv = rdt[i], dtu = dtv * ru[i];
        const float4* B4 = (const float4*)&sB[i][0];
        float4 q0 = B4[0], q1 = B4[1], q2 = B4[2], q3 = B4[3];
        float Bv[16] = {q0.x, q0.y, q0.z, q0.w, q1.x, q1.y, q1.z, q1.w,
                        q2.x, q2.y, q2.z, q2.w, q3.x, q3.y, q3.z, q3.w};
#pragma unroll
        for (int n = 0; n < 16; ++n) {
            float a = __builtin_amdgcn_exp2f(dtv * A2[n]);
            P[n] *= a;
            h[n] = a * h[n] + dtu * Bv[n];
        }
    }
    float* pp = Pg + ((size_t)(kb * 32 + ch)) * 12288 + d * 16;
    float* hp = Hg + ((size_t)(kb * 32 + ch)) * 12288 + d * 16;
#pragma unroll
    for (int q = 0; q < 4; ++q) {
        float4 pv = {P[4 * q], P[4 * q + 1], P[4 * q + 2], P[4 * q + 3]};
        float4 hv = {h[4 * q], h[4 * q + 1], h[4 * q + 2], h[4 * q + 3]};
        *(float4*)(pp + 4 * q) = pv;
        *(float4*)(hp + 4 * q) = hv;
    }
}

// prefix fold: h0[ch] for all chains. 8 kb * 12288 threads, unrolled over 31.
__global__ __launch_bounds__(256) void comb_k(const float* __restrict__ Pg,
                                              const float* __restrict__ Hg,
                                              float* __restrict__ H0g) {
    int t = blockIdx.x * 256 + threadIdx.x;   // 98304
    int kb = t / 12288, dn = t % 12288;
    size_t base = (size_t)kb * 32 * 12288 + dn;
    float pv[31], hv[31];
#pragma unroll
    for (int ch = 0; ch < 31; ++ch) {
        pv[ch] = Pg[base + (size_t)ch * 12288];
        hv[ch] = Hg[base + (size_t)ch * 12288];
    }
    float h = 0.f;
    H0g[base] = 0.f;
#pragma unroll
    for (int ch = 0; ch < 31; ++ch) {
        h = pv[ch] * h + hv[ch];
        H0g[base + (size_t)(ch + 1) * 12288] = h;
    }
}

__global__ __launch_bounds__(64) void scan_p2(const ushort* __restrict__ dtscan,
                                              const float* __restrict__ dblBC,
                                              const ushort* __restrict__ xcb,
                                              const ushort* __restrict__ xcwh,
                                              const float* __restrict__ alog,
                                              const float* __restrict__ H0g,
                                              ushort* __restrict__ y4b) {
    __shared__ float sB[32][16];
    __shared__ float sC[32][16];
    int lane = threadIdx.x;
    int d0 = blockIdx.x * 64, ch = blockIdx.y, kb = blockIdx.z;
    int k = kb & 3, b = kb >> 2;
    int d = d0 + lane;
    float A2[16];
    {
        const float4* ap = (const float4*)(alog + ((size_t)(k * 768 + d)) * 16);
#pragma unroll
        for (int q = 0; q < 4; ++q) {
            float4 v = ap[q];
            A2[4 * q + 0] = -__expf(v.x) * 1.44269504f;
            A2[4 * q + 1] = -__expf(v.y) * 1.44269504f;
            A2[4 * q + 2] = -__expf(v.z) * 1.44269504f;
            A2[4 * q + 3] = -__expf(v.w) * 1.44269504f;
        }
    }
    float h[16];
    {
        const float4* h0p =
            (const float4*)(H0g + ((size_t)(kb * 32 + ch)) * 12288 + d * 16);
#pragma unroll
        for (int q = 0; q < 4; ++q) {
            float4 hv = h0p[q];
            h[4 * q + 0] = hv.x; h[4 * q + 1] = hv.y;
            h[4 * q + 2] = hv.z; h[4 * q + 3] = hv.w;
        }
    }
    int l0 = ch * 32;
    const ushort* dts = dtscan + ((size_t)((k * 2 + b) * 1024 + l0)) * 768 + d;
    const ushort* ub = ((k & 1) ? xcwh : xcb) + (size_t)b * 786432 + d;
    const float* bcp = dblBC + (size_t)kb * 1024 * 32;
    ushort* yp = y4b + ((size_t)(kb * 1024 + l0)) * 768 + d;
    float rdt[32], ru[32], rB[8], rC[8];
#pragma unroll
    for (int i = 0; i < 32; ++i) rdt[i] = bf2f(dts[(size_t)i * 768]);
    if (k & 2) {
#pragma unroll
        for (int i = 0; i < 32; ++i)
            ru[i] = bf2f(ub[(size_t)(1023 - (l0 + i)) * 768]);
    } else {
#pragma unroll
        for (int i = 0; i < 32; ++i) ru[i] = bf2f(ub[(size_t)(l0 + i) * 768]);
    }
    int bi = lane >> 4, bn_ = lane & 15;
#pragma unroll
    for (int j = 0; j < 8; ++j) {
        rB[j] = bcp[(size_t)(l0 + bi + 4 * j) * 32 + bn_];
        rC[j] = bcp[(size_t)(l0 + bi + 4 * j) * 32 + 16 + bn_];
    }
#pragma unroll
    for (int j = 0; j < 8; ++j) {
        sB[bi + 4 * j][bn_] = rB[j];
        sC[bi + 4 * j][bn_] = rC[j];
    }
    __syncthreads();
#pragma unroll 4
    for (int i = 0; i < 32; ++i) {
        float dtv = rdt[i], dtu = dtv * ru[i];
        const float4* B4 = (const float4*)&sB[i][0];
        const float4* C4 = (const float4*)&sC[i][0];
        float4 q0 = B4[0], q1 = B4[1], q2 = B4[2], q3 = B4[3];
        float Bv[16] = {q0.x, q0.y, q0.z, q0.w, q1.x, q1.y, q1.z, q1.w,
                        q2.x, q2.y, q2.z, q2.w, q3.x, q3.y, q3.z, q3.w};
        float4 c0 = C4[0], c1 = C4[1], c2 = C4[2], c3 = C4[3];
        float Cv[16] = {c0.x, c0.y, c0.z, c0.w, c1.x, c1.y, c1.z, c1.w,
                        c2.x, c2.y, c2.z, c2.w, c3.x, c3.y, c3.z, c3.w};
        float y = 0.f;
#pragma unroll
        for (int n = 0; n < 16; ++n) {
            float a = __builtin_amdgcn_exp2f(dtv * A2[n]);
            h[n] = a * h[n] + dtu * Bv[n];
            y += h[n] * Cv[n];
        }
        yp[(size_t)i * 768] = f2bf(y);
    }
}

// ------- sum 4 dirs (row-gather from scan order) + D*u, out-LN, *silu(z) ---------
__global__ __launch_bounds__(256) void fuse_out_k(const ushort* __restrict__ y4b,
                                                  const ushort* __restrict__ xcb,
                                                  const float* __restrict__ xz,
                                                  const float* __restrict__ ds,
                                                  const float* __restrict__ onw,
                                                  const float* __restrict__ onb,
                                                  ushort* __restrict__ g) {
    int w = threadIdx.x >> 6, lane = threadIdx.x & 63;
    int row = blockIdx.x * 4 + w;      // grid 512
    int b = row >> 10, p = row & 1023;
    int l0 = scan_pos(0, p), l1 = scan_pos(1, p);
    int l2 = scan_pos(2, p), l3 = scan_pos(3, p);
    const ushort* y0 = y4b + ((size_t)((b * 4 + 0) * 1024 + l0)) * 768;
    const ushort* y1 = y4b + ((size_t)((b * 4 + 1) * 1024 + l1)) * 768;
    const ushort* y2 = y4b + ((size_t)((b * 4 + 2) * 1024 + l2)) * 768;
    const ushort* y3 = y4b + ((size_t)((b * 4 + 3) * 1024 + l3)) * 768;
    float v[12], s1 = 0.f, s2 = 0.f;
#pragma unroll
    for (int q = 0; q < 12; ++q) {
        int d = lane + 64 * q;
        float u = bf2f(xcb[(size_t)row * 768 + d]);
        float dsum = ds[d] + ds[768 + d] + ds[1536 + d] + ds[2304 + d];
        float val = dsum * u + bf2f(y0[d]) + bf2f(y1[d]) + bf2f(y2[d]) + bf2f(y3[d]);
        v[q] = val; s1 += val; s2 += val * val;
    }
#pragma unroll
    for (int m = 1; m < 64; m <<= 1) {
        s1 += __shfl_xor(s1, m); s2 += __shfl_xor(s2, m);
    }
    float mean = s1 * (1.f / 768.f);
    float rstd = rsqrtf(s2 * (1.f / 768.f) - mean * mean + 1e-5f);
#pragma unroll
    for (int q = 0; q < 12; ++q) {
        int d = lane + 64 * q;
        float zz = xz[(size_t)row * 1536 + 768 + d];
        float sil = zz * sigmoidf_(zz);
        g[(size_t)row * 768 + d] = f2bf(((v[q] - mean) * rstd * onw[d] + onb[d]) * sil);
    }
}

extern "C" void kernel_launch(void* const* d_in, const int* in_sizes, int n_in,
                              void* d_out, int out_size, void* d_ws, size_t ws_size,
                              hipStream_t stream) {
    const float* x    = (const float*)d_in[0];
    const float* skip = (const float*)d_in[1];
    const float* pew  = (const float*)d_in[2];
    const float* pnw  = (const float*)d_in[3];
    const float* pnb  = (const float*)d_in[4];
    const float* lpw  = (const float*)d_in[5];
    const float* lpb  = (const float*)d_in[6];
    const float* blw  = (const float*)d_in[7];
    const float* blb  = (const float*)d_in[8];
    const float* inw  = (const float*)d_in[9];
    const float* cw   = (const float*)d_in[10];
    const float* cb   = (const float*)d_in[11];
    const float* xpw  = (const float*)d_in[12];
    const float* dtw  = (const float*)d_in[13];
    const float* dtbi = (const float*)d_in[14];
    const float* alog = (const float*)d_in[15];
    const float* ds   = (const float*)d_in[16];
    const float* onw  = (const float*)d_in[17];
    const float* onb  = (const float*)d_in[18];
    const float* ow   = (const float*)d_in[19];
    float* out = (float*)d_out;

    char* base = (char*)d_ws;
    auto alloc = [&](size_t bytes) -> char* {
        char* p = base;
        base += (bytes + 255) & ~(size_t)255;
        return p;
    };
    float*  xh    = (float*)alloc(2048 * 384 * 4);
    ushort* hbuf  = (ushort*)alloc(2048 * 768 * 2);
    float*  xz    = (float*)alloc((size_t)2048 * 1536 * 4);
    ushort* xcb   = (ushort*)alloc(2048 * 768 * 2);
    ushort* xcwh  = (ushort*)alloc(2048 * 768 * 2);
    float*  dblBC = (float*)alloc(8192 * 32 * 4);
    ushort* dtrb  = (ushort*)alloc((size_t)4 * 2048 * 32 * 2);
    ushort* dtscan= (ushort*)alloc((size_t)4 * 2048 * 768 * 2);
    ushort* y4b   = (ushort*)alloc((size_t)8192 * 768 * 2);
    float*  Pg    = (float*)alloc((size_t)8 * 32 * 12288 * 4);
    float*  Hg    = (float*)alloc((size_t)8 * 32 * 12288 * 4);
    float*  H0g   = (float*)alloc((size_t)8 * 32 * 12288 * 4);
    ushort* xspe  = (ushort*)alloc(512 * 768 * 2);
    float*  t1    = (float*)alloc(512 * 1536 * 4);
    ushort* wpe   = (ushort*)alloc((size_t)1536 * 768 * 2);
    ushort* wlp   = (ushort*)alloc(384 * 768 * 2);
    ushort* winb  = (ushort*)alloc((size_t)2 * 1536 * 384 * 2);
    ushort* wob   = (ushort*)alloc((size_t)2 * 384 * 768 * 2);
    ushort* wxpp  = (ushort*)alloc((size_t)2 * 256 * 768 * 2);
    ushort* wdtp  = (ushort*)alloc((size_t)2 * 4 * 768 * 32 * 2);

    cvt_all_k<<<3744, 256, 0, stream>>>(pew, lpw, inw, ow, xpw, dtw,
                                        wpe, wlp, winb, wob, wxpp, wdtp);

    // ---- Stage A ----
    tr_x_k<<<dim3(8, 24, 2), 256, 0, stream>>>(x, xspe);
    gemm_t<64><<<dim3(24, 4), 256, 0, stream>>>(xspe, wpe, nullptr, nullptr, t1,
                                                nullptr, nullptr, nullptr,
                                                512, 1536, 768, 0, 0, 0, 0, 0);
    peskip_k<<<1280, 256, 0, stream>>>(t1, pnw, pnb, skip, hbuf);
    gemm_t<64><<<dim3(6, 16), 256, 0, stream>>>(hbuf, wlp, lpb, nullptr, xh,
                                                nullptr, nullptr, nullptr,
                                                2048, 384, 768, 0, 0, 0, 0, 0);

    // ---- 2 VSS blocks ----
    for (int blk = 0; blk < 2; ++blk) {
        const ushort* inw_i = winb + (size_t)blk * 1536 * 384;
        const float*  cw_i  = cw + (size_t)blk * 768 * 9;
        const float*  cb_i  = cb + (size_t)blk * 768;
        const ushort* xpw_i = wxpp + (size_t)blk * 256 * 768;
        const ushort* dtw_i = wdtp + (size_t)blk * 4 * 768 * 32;
        const float*  dtb_i = dtbi + (size_t)blk * 4 * 768;
        const float*  al_i  = alog + (size_t)blk * 4 * 768 * 16;
        const float*  ds_i  = ds + (size_t)blk * 4 * 768;
        const float*  onw_i = onw + (size_t)blk * 768;
        const float*  onb_i = onb + (size_t)blk * 768;
        const ushort* ow_i  = wob + (size_t)blk * 384 * 768;

        ln_rows_384<<<512, 256, 0, stream>>>(xh, blw + blk * 384, blb + blk * 384,
                                             hbuf);
        gemm_t<128><<<dim3(12, 16), 256, 0, stream>>>(hbuf, inw_i, nullptr,
                                                      nullptr, xz, nullptr,
                                                      nullptr, nullptr,
                                                      2048, 1536, 384,
                                                      0, 0, 0, 0, 0);
        conv_silu_k<<<2048, 256, 0, stream>>>(xz, cw_i, cb_i, xcb, xcwh);
        gemm_t<64><<<dim3(4, 16), 256, 0, stream>>>(xcb, xpw_i, nullptr, nullptr,
                                                    nullptr, nullptr, dblBC, dtrb,
                                                    2048, 256, 768, 0, 0, 0, 0, 2);
        gemm_t<64><<<dim3(12, 16, 4), 256, 0, stream>>>(dtrb, dtw_i, dtb_i,
                                                        nullptr, nullptr, dtscan,
                                                        nullptr, nullptr,
                                                        2048, 768, 32,
                                                        2048 * 32, 768 * 32, 768,
                                                        0, 1);
        scan_p1<<<dim3(12, 31, 8), 64, 0, stream>>>(dtscan, dblBC, xcb, xcwh,
                                                    al_i, Pg, Hg);
        comb_k<<<384, 256, 0, stream>>>(Pg, Hg, H0g);
        scan_p2<<<dim3(12, 32, 8), 64, 0, stream>>>(dtscan, dblBC, xcb, xcwh,
                                                    al_i, H0g, y4b);
        fuse_out_k<<<512, 256, 0, stream>>>(y4b, xcb, xz, ds_i, onw_i, onb_i,
                                            hbuf);
        gemm_t<64><<<dim3(6, 16), 256, 0, stream>>>(hbuf, ow_i, nullptr, xh, xh,
                                                    nullptr, nullptr, nullptr,
                                                    2048, 384, 768, 0, 0, 0, 0, 0);
    }

    tr_out_k<<<dim3(32, 12, 2), 256, 0, stream>>>(xh, out);
}

// Round 8
// 464.566 us; speedup vs baseline: 1.3421x; 1.3421x over previous
//
#include <hip/hip_runtime.h>
#include <math.h>

// Problem constants: B=2, H=W=32 (after expand), L=1024, out_dim=384, Di=768,
// K=4 directions, N=16 state, R=24, depth=2. fp32 in/out; bf16 MFMA GEMMs.

typedef __attribute__((ext_vector_type(8))) short s8v;   // 8 bf16 = 4 VGPRs
typedef __attribute__((ext_vector_type(4))) float f4v;

static __device__ __forceinline__ float sigmoidf_(float x) {
    return 1.f / (1.f + __expf(-x));
}
static __device__ __forceinline__ ushort f2bf(float x) {
    unsigned u = __float_as_uint(x);
    return (ushort)((u + 0x7fff + ((u >> 16) & 1)) >> 16);   // RNE
}
static __device__ __forceinline__ float bf2f(ushort u) {
    return __uint_as_float(((unsigned)u) << 16);
}

// Scan-order <-> spatial-position map. Involution for all k.
static __device__ __forceinline__ int scan_pos(int k, int l) {
    int m = (k & 2) ? (1023 - l) : l;
    return (k & 1) ? (((m & 31) << 5) | (m >> 5)) : m;
}

// ---------------- all weight conversions fp32->bf16 in ONE kernel ----------------
__global__ __launch_bounds__(256) void cvt_all_k(
    const float* __restrict__ pew, const float* __restrict__ lpw,
    const float* __restrict__ inw, const float* __restrict__ ow,
    const float* __restrict__ xpw, const float* __restrict__ dtw,
    ushort* __restrict__ wpe, ushort* __restrict__ wlp,
    ushort* __restrict__ winb, ushort* __restrict__ wob,
    ushort* __restrict__ wxpp, ushort* __restrict__ wdtp) {
    int g = blockIdx.x * 256 + threadIdx.x;
    if (g < 811008) {
        const float* s; ushort* d; int off;
        if (g < 294912)      { s = pew;  d = wpe;  off = g; }
        else if (g < 368640) { s = lpw;  d = wlp;  off = g - 294912; }
        else if (g < 663552) { s = inw;  d = winb; off = g - 368640; }
        else                 { s = ow;   d = wob;  off = g - 663552; }
        float4 v = ((const float4*)s)[off];
        ushort4 o = {f2bf(v.x), f2bf(v.y), f2bf(v.z), f2bf(v.w)};
        ((ushort4*)d)[off] = o;
    } else if (g < 909312) {
        int e = g - 811008;
        int blkb = e / 49152, rem = e % 49152;
        int n = rem / 192, q = rem % 192;
        int k = n >> 6, c = n & 63;
        ushort4 o = {0, 0, 0, 0};
        if (c < 56) {
            float4 v = *(const float4*)(xpw +
                ((size_t)((blkb * 4 + k) * 56 + c)) * 768 + q * 4);
            o = {f2bf(v.x), f2bf(v.y), f2bf(v.z), f2bf(v.w)};
        }
        ((ushort4*)wxpp)[e] = o;
    } else {
        int e = g - 909312;          // 49152 groups
        int rowk = e >> 3, q = e & 7;
        ushort4 o = {0, 0, 0, 0};
        if (q < 6) {
            float4 v = *(const float4*)(dtw + (size_t)rowk * 24 + q * 4);
            o = {f2bf(v.x), f2bf(v.y), f2bf(v.z), f2bf(v.w)};
        }
        ((ushort4*)wdtp)[e] = o;
    }
}

// ---------------- tiled transpose: x (B,768,256) -> (B*256,768) bf16 -------------
__global__ __launch_bounds__(256) void tr_x_k(const float* __restrict__ x,
                                              ushort* __restrict__ o) {
    __shared__ float tile[32][33];
    int b = blockIdx.z, c0 = blockIdx.y * 32, s0 = blockIdx.x * 32;
    int tx = threadIdx.x & 31, ty = threadIdx.x >> 5;
    for (int i = ty; i < 32; i += 8)
        tile[i][tx] = x[((size_t)(b * 768 + c0 + i)) * 256 + s0 + tx];
    __syncthreads();
    for (int i = ty; i < 32; i += 8)
        o[((size_t)(b * 256 + s0 + i)) * 768 + c0 + tx] = f2bf(tile[tx][i]);
}

// ---------------- merged: pe_ln (blocks 0..511) + tr_skip (blocks 512..1279) -----
__global__ __launch_bounds__(256) void peskip_k(const float* __restrict__ t1,
                                                const float* __restrict__ pnw,
                                                const float* __restrict__ pnb,
                                                const float* __restrict__ skip,
                                                ushort* __restrict__ cin) {
    __shared__ float tile[32][33];
    int bx = blockIdx.x;
    if (bx < 512) {
        int w = threadIdx.x >> 6, lane = threadIdx.x & 63;
        int row = bx * 4 + w;
        int b = row >> 10, p = row & 1023;
        int r = p >> 5, col = p & 31;
        int i = r >> 1, a = r & 1, j = col >> 1, b2 = col & 1;
        const float* src =
            t1 + ((size_t)(b * 256 + i * 16 + j)) * 1536 + (a * 2 + b2) * 384;
        float v[6], s1 = 0.f, s2 = 0.f;
#pragma unroll
        for (int q = 0; q < 6; ++q) {
            v[q] = src[lane + 64 * q];
            s1 += v[q]; s2 += v[q] * v[q];
        }
#pragma unroll
        for (int m = 1; m < 64; m <<= 1) {
            s1 += __shfl_xor(s1, m); s2 += __shfl_xor(s2, m);
        }
        float mean = s1 * (1.f / 384.f);
        float rstd = rsqrtf(s2 * (1.f / 384.f) - mean * mean + 1e-5f);
        ushort* o = cin + (size_t)row * 768;
#pragma unroll
        for (int q = 0; q < 6; ++q) {
            int c = lane + 64 * q;
            o[c] = f2bf((v[q] - mean) * rstd * pnw[c] + pnb[c]);
        }
    } else {
        int idx = bx - 512;                 // 768 blocks: b (2) x c0 (12) x s0 (32)
        int b = idx / 384, rem = idx % 384;
        int c0 = (rem / 32) * 32, s0 = (rem % 32) * 32;
        int tx = threadIdx.x & 31, ty = threadIdx.x >> 5;
        for (int i = ty; i < 32; i += 8)
            tile[i][tx] = skip[((size_t)(b * 384 + c0 + i)) * 1024 + s0 + tx];
        __syncthreads();
        for (int i = ty; i < 32; i += 8)
            cin[((size_t)(b * 1024 + s0 + i)) * 768 + 384 + c0 + tx] =
                f2bf(tile[tx][i]);
    }
}

// ---------------- tiled transpose: xh (B*1024,384) -> out (B,384,1024) fp32 ------
__global__ __launch_bounds__(256) void tr_out_k(const float* __restrict__ xh,
                                                float* __restrict__ out) {
    __shared__ float tile[32][33];
    int b = blockIdx.z, p0 = blockIdx.x * 32, c0 = blockIdx.y * 32;
    int tx = threadIdx.x & 31, ty = threadIdx.x >> 5;
    for (int i = ty; i < 32; i += 8)
        tile[i][tx] = xh[((size_t)(b * 1024 + p0 + i)) * 384 + c0 + tx];
    __syncthreads();
    for (int i = ty; i < 32; i += 8)
        out[((size_t)(b * 384 + c0 + i)) * 1024 + p0 + tx] = tile[tx][i];
}

// ---------------- bf16 NT MFMA GEMM, templated tile width, pipelined -------------
// BN=128: 4 waves 2x2, wave 64x64. BN=64: 4 waves stacked in M, wave 32x64.
// Double-buffered LDS; next tile's global loads issued before MFMAs (vmcnt wait
// lands after). mode 0: Cf=acc(+bias)(+res). mode 1 (dt-proj, z=k): CONTIGUOUS
// Cb[row*768+col] = bf16(softplus(acc+bias)) (fast intrinsics; scatter moved to
// dt_perm_k after R7's 65us scattered-2B-store regression).
// mode 2 (xproj): dtrb bf16 + dblBC fp32 scan-order scatter (small, 32 cols).
template <int BN>
__global__ __launch_bounds__(256) void gemm_t(const ushort* __restrict__ A,
                                              const ushort* __restrict__ B,
                                              const float* __restrict__ bias,
                                              const float* __restrict__ res,
                                              float* __restrict__ Cf,
                                              ushort* __restrict__ Cb,
                                              float* __restrict__ dblBC,
                                              ushort* __restrict__ dtrb,
                                              int M, int N, int K,
                                              long sAz, long sBz, long sBiz,
                                              long sCz, int mode) {
    constexpr int MI = (BN == 128) ? 4 : 2;
    __shared__ ushort Als[2][128][40];   // 80 B rows: 20-bank stride, 2-way free
    __shared__ ushort Bls[2][BN][40];
    A += (size_t)blockIdx.z * sAz;
    B += (size_t)blockIdx.z * sBz;
    if (Cf) Cf += (size_t)blockIdx.z * sCz;
    if (Cb) Cb += (size_t)blockIdx.z * sCz;
    if (bias) bias += (size_t)blockIdx.z * sBiz;
    int t = threadIdx.x;
    int bm = blockIdx.y * 128, bn = blockIdx.x * BN;
    int lane = t & 63, w = t >> 6;
    int wm = (BN == 128) ? (w & 1) * 64 : w * 32;
    int wn = (BN == 128) ? (w >> 1) * 64 : 0;
    int r16 = lane & 15, quad = lane >> 4;
    int srow = t >> 1, shalf = t & 1;
    int brow = (BN == 128) ? (t >> 1) : (t >> 2);
    int bq   = (BN == 128) ? (t & 1) * 16 : (t & 3) * 8;
    f4v acc[MI][4] = {};
    const ushort* Ag = A + (size_t)(bm + srow) * K + shalf * 16;
    const ushort* Bg = B + (size_t)(bn + brow) * K + bq;
    int nt = K >> 5;
    uint4 a0, a1, b0, b1;
    a0 = *(const uint4*)(Ag);
    a1 = *(const uint4*)(Ag + 8);
    b0 = *(const uint4*)(Bg);
    if (BN == 128) b1 = *(const uint4*)(Bg + 8);
    *(uint4*)&Als[0][srow][shalf * 16] = a0;
    *(uint4*)&Als[0][srow][shalf * 16 + 8] = a1;
    *(uint4*)&Bls[0][brow][bq] = b0;
    if (BN == 128) *(uint4*)&Bls[0][brow][bq + 8] = b1;
    for (int it = 0; it < nt; ++it) {
        int buf = it & 1;
        __syncthreads();                  // LDS[buf] ready; prev reads of buf^1 done
        if (it + 1 < nt) {                // issue next tile's loads
            int k0 = (it + 1) << 5;
            a0 = *(const uint4*)(Ag + k0);
            a1 = *(const uint4*)(Ag + k0 + 8);
            b0 = *(const uint4*)(Bg + k0);
            if (BN == 128) b1 = *(const uint4*)(Bg + k0 + 8);
        }
        s8v af[MI], bfr[4];
#pragma unroll
        for (int i = 0; i < MI; ++i)
            af[i] = *(const s8v*)&Als[buf][wm + i * 16 + r16][quad * 8];
#pragma unroll
        for (int j = 0; j < 4; ++j)
            bfr[j] = *(const s8v*)&Bls[buf][wn + j * 16 + r16][quad * 8];
#pragma unroll
        for (int i = 0; i < MI; ++i)
#pragma unroll
            for (int j = 0; j < 4; ++j)
                acc[i][j] = __builtin_amdgcn_mfma_f32_16x16x32_bf16(
                    af[i], bfr[j], acc[i][j], 0, 0, 0);
        if (it + 1 < nt) {                // vmcnt wait lands here, after MFMAs
            *(uint4*)&Als[buf ^ 1][srow][shalf * 16] = a0;
            *(uint4*)&Als[buf ^ 1][srow][shalf * 16 + 8] = a1;
            *(uint4*)&Bls[buf ^ 1][brow][bq] = b0;
            if (BN == 128) *(uint4*)&Bls[buf ^ 1][brow][bq + 8] = b1;
        }
    }
    // D mapping: col=lane&15, row=quad*4+reg (m89-verified)
#pragma unroll
    for (int i = 0; i < MI; ++i) {
        int row0 = bm + wm + i * 16 + quad * 4;
#pragma unroll
        for (int j = 0; j < 4; ++j) {
            int col = bn + wn + j * 16 + r16;
            float bv = bias ? bias[col] : 0.f;
#pragma unroll
            for (int r = 0; r < 4; ++r) {
                int row = row0 + r;
                float v = acc[i][j][r] + bv;
                if (mode == 0) {
                    if (res) v += res[(size_t)row * N + col];
                    Cf[(size_t)row * N + col] = v;
                } else if (mode == 1) {
                    v = (v > 20.f) ? v : __logf(1.f + __expf(v));
                    Cb[(size_t)row * N + col] = f2bf(v);
                } else {
                    int k = col >> 6, c = col & 63;
                    int b = row >> 10, p = row & 1023;
                    if (c < 32)
                        dtrb[((size_t)k * 2048 + row) * 32 + c] =
                            f2bf((c < 24) ? v : 0.f);
                    if (c >= 24 && c < 56) {
                        int l = scan_pos(k, p);
                        dblBC[(((size_t)(b * 4 + k)) * 1024 + l) * 32 + (c - 24)] = v;
                    }
                }
            }
        }
    }
}

// ---- dt row-permute: dtsp [k][b*1024+p][768] -> dtscan [(k*2+b)*1024+l][768] ----
// Row-granular gather: both sides 1536 B contiguous rows; fully coalesced.
__global__ __launch_bounds__(256) void dt_perm_k(const ushort* __restrict__ dtsp,
                                                 ushort* __restrict__ dtscan) {
    int r = blockIdx.x * 2 + (threadIdx.x >> 7);   // 8192 rows, grid 4096
    int t = threadIdx.x & 127;
    int l = r & 1023;
    int kb2 = r >> 10;                 // k*2 + b
    int k = kb2 >> 1, b = kb2 & 1;
    int p = scan_pos(k, l);
    const uint* s = (const uint*)(dtsp + ((size_t)(k * 2048 + b * 1024 + p)) * 768);
    uint* d = (uint*)(dtscan + (size_t)r * 768);
    d[t] = s[t];
    d[t + 128] = s[t + 128];
    d[t + 256] = s[t + 256];
}

// ---------------- row LayerNorm over 384 cols -> bf16 (wave/row) ----------------
__global__ __launch_bounds__(256) void ln_rows_384(const float* __restrict__ in,
                                                   const float* __restrict__ wgt,
                                                   const float* __restrict__ bb,
                                                   ushort* __restrict__ out) {
    int w = threadIdx.x >> 6, lane = threadIdx.x & 63;
    int row = blockIdx.x * 4 + w;      // grid 512
    const float* x = in + (size_t)row * 384;
    float v[6], s1 = 0.f, s2 = 0.f;
#pragma unroll
    for (int q = 0; q < 6; ++q) {
        v[q] = x[lane + 64 * q];
        s1 += v[q]; s2 += v[q] * v[q];
    }
#pragma unroll
    for (int m = 1; m < 64; m <<= 1) {
        s1 += __shfl_xor(s1, m); s2 += __shfl_xor(s2, m);
    }
    float mean = s1 * (1.f / 384.f);
    float rstd = rsqrtf(s2 * (1.f / 384.f) - mean * mean + 1e-5f);
#pragma unroll
    for (int q = 0; q < 6; ++q) {
        int c = lane + 64 * q;
        out[(size_t)row * 384 + c] = f2bf((v[q] - mean) * rstd * wgt[c] + bb[c]);
    }
}

// ------- depthwise 3x3 conv + bias + SiLU -> xcb (spatial) + xcwh (transposed) ---
__global__ __launch_bounds__(256) void conv_silu_k(const float* __restrict__ xz,
                                                   const float* __restrict__ cw,
                                                   const float* __restrict__ cb,
                                                   ushort* __restrict__ xcb,
                                                   ushort* __restrict__ xcwh) {
    int row = blockIdx.x;
    int b = row >> 10, p = row & 1023;
    int r = p >> 5, col = p & 31;
    int mwh = ((p & 31) << 5) | (p >> 5);
    for (int d = threadIdx.x; d < 768; d += 256) {
        float acc = cb[d];
#pragma unroll
        for (int dy = 0; dy < 3; ++dy) {
            int rr = r + dy - 1;
            if ((unsigned)rr > 31u) continue;
#pragma unroll
            for (int dx = 0; dx < 3; ++dx) {
                int cc = col + dx - 1;
                if ((unsigned)cc > 31u) continue;
                acc += cw[d * 9 + dy * 3 + dx] *
                       xz[((size_t)(b * 1024 + rr * 32 + cc)) * 1536 + d];
            }
        }
        float o = acc * sigmoidf_(acc);
        ushort ob = f2bf(o);
        xcb[(size_t)row * 768 + d] = ob;
        xcwh[((size_t)(b * 1024 + mwh)) * 768 + d] = ob;
    }
}

// ======== selective scan: fully sequential IO (scan-order layouts) ========
// dtscan bf16 [(k*2+b)*1024+l][768]; u: xcb (k even) / xcwh (k odd), row l or
// 1023-l (k>=2); dblBC fp32 scan-order; y4b written in scan order.
// Chunks: 32 x 32 steps. Pg/Hg/H0g: [(kb*32+ch)*12288 + d*16 + n].

__global__ __launch_bounds__(64) void scan_p1(const ushort* __restrict__ dtscan,
                                              const float* __restrict__ dblBC,
                                              const ushort* __restrict__ xcb,
                                              const ushort* __restrict__ xcwh,
                                              const float* __restrict__ alog,
                                              float* __restrict__ Pg,
                                              float* __restrict__ Hg) {
    __shared__ float sB[32][16];
    int lane = threadIdx.x;
    int d0 = blockIdx.x * 64, ch = blockIdx.y, kb = blockIdx.z;
    int k = kb & 3, b = kb >> 2;
    int d = d0 + lane;
    float A2[16];
    {
        const float4* ap = (const float4*)(alog + ((size_t)(k * 768 + d)) * 16);
#pragma unroll
        for (int q = 0; q < 4; ++q) {
            float4 v = ap[q];
            A2[4 * q + 0] = -__expf(v.x) * 1.44269504f;
            A2[4 * q + 1] = -__expf(v.y) * 1.44269504f;
            A2[4 * q + 2] = -__expf(v.z) * 1.44269504f;
            A2[4 * q + 3] = -__expf(v.w) * 1.44269504f;
        }
    }
    int l0 = ch * 32;
    const ushort* dts = dtscan + ((size_t)((k * 2 + b) * 1024 + l0)) * 768 + d;
    const ushort* ub = ((k & 1) ? xcwh : xcb) + (size_t)b * 786432 + d;
    const float* bcp = dblBC + (size_t)kb * 1024 * 32;
    float rdt[32], ru[32], rB[8];
#pragma unroll
    for (int i = 0; i < 32; ++i) rdt[i] = bf2f(dts[(size_t)i * 768]);
    if (k & 2) {
#pragma unroll
        for (int i = 0; i < 32; ++i)
            ru[i] = bf2f(ub[(size_t)(1023 - (l0 + i)) * 768]);
    } else {
#pragma unroll
        for (int i = 0; i < 32; ++i) ru[i] = bf2f(ub[(size_t)(l0 + i) * 768]);
    }
    int bi = lane >> 4, bn_ = lane & 15;
#pragma unroll
    for (int j = 0; j < 8; ++j)
        rB[j] = bcp[(size_t)(l0 + bi + 4 * j) * 32 + bn_];
#pragma unroll
    for (int j = 0; j < 8; ++j) sB[bi + 4 * j][bn_] = rB[j];
    __syncthreads();
    float h[16], P[16];
#pragma unroll
    for (int n = 0; n < 16; ++n) { h[n] = 0.f; P[n] = 1.f; }
#pragma unroll 4
    for (int i = 0; i < 32; ++i) {
        float dtv = rdt[i], dtu = dtv * ru[i];
        const float4* B4 = (const float4*)&sB[i][0];
        float4 q0 = B4[0], q1 = B4[1], q2 = B4[2], q3 = B4[3];
        float Bv[16] = {q0.x, q0.y, q0.z, q0.w, q1.x, q1.y, q1.z, q1.w,
                        q2.x, q2.y, q2.z, q2.w, q3.x, q3.y, q3.z, q3.w};
#pragma unroll
        for (int n = 0; n < 16; ++n) {
            float a = __builtin_amdgcn_exp2f(dtv * A2[n]);
            P[n] *= a;
            h[n] = a * h[n] + dtu * Bv[n];
        }
    }
    float* pp = Pg + ((size_t)(kb * 32 + ch)) * 12288 + d * 16;
    float* hp = Hg + ((size_t)(kb * 32 + ch)) * 12288 + d * 16;
#pragma unroll
    for (int q = 0; q < 4; ++q) {
        float4 pv = {P[4 * q], P[4 * q + 1], P[4 * q + 2], P[4 * q + 3]};
        float4 hv = {h[4 * q], h[4 * q + 1], h[4 * q + 2], h[4 * q + 3]};
        *(float4*)(pp + 4 * q) = pv;
        *(float4*)(hp + 4 * q) = hv;
    }
}

// prefix fold: h0[ch] for all chains. 8 kb * 12288 threads, unrolled over 31.
__global__ __launch_bounds__(256) void comb_k(const float* __restrict__ Pg,
                                              const float* __restrict__ Hg,
                                              float* __restrict__ H0g) {
    int t = blockIdx.x * 256 + threadIdx.x;   // 98304
    int kb = t / 12288, dn = t % 12288;
    size_t base = (size_t)kb * 32 * 12288 + dn;
    float pv[31], hv[31];
#pragma unroll
    for (int ch = 0; ch < 31; ++ch) {
        pv[ch] = Pg[base + (size_t)ch * 12288];
        hv[ch] = Hg[base + (size_t)ch * 12288];
    }
    float h = 0.f;
    H0g[base] = 0.f;
#pragma unroll
    for (int ch = 0; ch < 31; ++ch) {
        h = pv[ch] * h + hv[ch];
        H0g[base + (size_t)(ch + 1) * 12288] = h;
    }
}

__global__ __launch_bounds__(64) void scan_p2(const ushort* __restrict__ dtscan,
                                              const float* __restrict__ dblBC,
                                              const ushort* __restrict__ xcb,
                                              const ushort* __restrict__ xcwh,
                                              const float* __restrict__ alog,
                                              const float* __restrict__ H0g,
                                              ushort* __restrict__ y4b) {
    __shared__ float sB[32][16];
    __shared__ float sC[32][16];
    int lane = threadIdx.x;
    int d0 = blockIdx.x * 64, ch = blockIdx.y, kb = blockIdx.z;
    int k = kb & 3, b = kb >> 2;
    int d = d0 + lane;
    float A2[16];
    {
        const float4* ap = (const float4*)(alog + ((size_t)(k * 768 + d)) * 16);
#pragma unroll
        for (int q = 0; q < 4; ++q) {
            float4 v = ap[q];
            A2[4 * q + 0] = -__expf(v.x) * 1.44269504f;
            A2[4 * q + 1] = -__expf(v.y) * 1.44269504f;
            A2[4 * q + 2] = -__expf(v.z) * 1.44269504f;
            A2[4 * q + 3] = -__expf(v.w) * 1.44269504f;
        }
    }
    float h[16];
    {
        const float4* h0p =
            (const float4*)(H0g + ((size_t)(kb * 32 + ch)) * 12288 + d * 16);
#pragma unroll
        for (int q = 0; q < 4; ++q) {
            float4 hv = h0p[q];
            h[4 * q + 0] = hv.x; h[4 * q + 1] = hv.y;
            h[4 * q + 2] = hv.z; h[4 * q + 3] = hv.w;
        }
    }
    int l0 = ch * 32;
    const ushort* dts = dtscan + ((size_t)((k * 2 + b) * 1024 + l0)) * 768 + d;
    const ushort* ub = ((k & 1) ? xcwh : xcb) + (size_t)b * 786432 + d;
    const float* bcp = dblBC + (size_t)kb * 1024 * 32;
    ushort* yp = y4b + ((size_t)(kb * 1024 + l0)) * 768 + d;
    float rdt[32], ru[32], rB[8], rC[8];
#pragma unroll
    for (int i = 0; i < 32; ++i) rdt[i] = bf2f(dts[(size_t)i * 768]);
    if (k & 2) {
#pragma unroll
        for (int i = 0; i < 32; ++i)
            ru[i] = bf2f(ub[(size_t)(1023 - (l0 + i)) * 768]);
    } else {
#pragma unroll
        for (int i = 0; i < 32; ++i) ru[i] = bf2f(ub[(size_t)(l0 + i) * 768]);
    }
    int bi = lane >> 4, bn_ = lane & 15;
#pragma unroll
    for (int j = 0; j < 8; ++j) {
        rB[j] = bcp[(size_t)(l0 + bi + 4 * j) * 32 + bn_];
        rC[j] = bcp[(size_t)(l0 + bi + 4 * j) * 32 + 16 + bn_];
    }
#pragma unroll
    for (int j = 0; j < 8; ++j) {
        sB[bi + 4 * j][bn_] = rB[j];
        sC[bi + 4 * j][bn_] = rC[j];
    }
    __syncthreads();
#pragma unroll 4
    for (int i = 0; i < 32; ++i) {
        float dtv = rdt[i], dtu = dtv * ru[i];
        const float4* B4 = (const float4*)&sB[i][0];
        const float4* C4 = (const float4*)&sC[i][0];
        float4 q0 = B4[0], q1 = B4[1], q2 = B4[2], q3 = B4[3];
        float Bv[16] = {q0.x, q0.y, q0.z, q0.w, q1.x, q1.y, q1.z, q1.w,
                        q2.x, q2.y, q2.z, q2.w, q3.x, q3.y, q3.z, q3.w};
        float4 c0 = C4[0], c1 = C4[1], c2 = C4[2], c3 = C4[3];
        float Cv[16] = {c0.x, c0.y, c0.z, c0.w, c1.x, c1.y, c1.z, c1.w,
                        c2.x, c2.y, c2.z, c2.w, c3.x, c3.y, c3.z, c3.w};
        float y = 0.f;
#pragma unroll
        for (int n = 0; n < 16; ++n) {
            float a = __builtin_amdgcn_exp2f(dtv * A2[n]);
            h[n] = a * h[n] + dtu * Bv[n];
            y += h[n] * Cv[n];
        }
        yp[(size_t)i * 768] = f2bf(y);
    }
}

// ------- sum 4 dirs (row-gather from scan order) + D*u, out-LN, *silu(z) ---------
__global__ __launch_bounds__(256) void fuse_out_k(const ushort* __restrict__ y4b,
                                                  const ushort* __restrict__ xcb,
                                                  const float* __restrict__ xz,
                                                  const float* __restrict__ ds,
                                                  const float* __restrict__ onw,
                                                  const float* __restrict__ onb,
                                                  ushort* __restrict__ g) {
    int w = threadIdx.x >> 6, lane = threadIdx.x & 63;
    int row = blockIdx.x * 4 + w;      // grid 512
    int b = row >> 10, p = row & 1023;
    int l0 = scan_pos(0, p), l1 = scan_pos(1, p);
    int l2 = scan_pos(2, p), l3 = scan_pos(3, p);
    const ushort* y0 = y4b + ((size_t)((b * 4 + 0) * 1024 + l0)) * 768;
    const ushort* y1 = y4b + ((size_t)((b * 4 + 1) * 1024 + l1)) * 768;
    const ushort* y2 = y4b + ((size_t)((b * 4 + 2) * 1024 + l2)) * 768;
    const ushort* y3 = y4b + ((size_t)((b * 4 + 3) * 1024 + l3)) * 768;
    float v[12], s1 = 0.f, s2 = 0.f;
#pragma unroll
    for (int q = 0; q < 12; ++q) {
        int d = lane + 64 * q;
        float u = bf2f(xcb[(size_t)row * 768 + d]);
        float dsum = ds[d] + ds[768 + d] + ds[1536 + d] + ds[2304 + d];
        float val = dsum * u + bf2f(y0[d]) + bf2f(y1[d]) + bf2f(y2[d]) + bf2f(y3[d]);
        v[q] = val; s1 += val; s2 += val * val;
    }
#pragma unroll
    for (int m = 1; m < 64; m <<= 1) {
        s1 += __shfl_xor(s1, m); s2 += __shfl_xor(s2, m);
    }
    float mean = s1 * (1.f / 768.f);
    float rstd = rsqrtf(s2 * (1.f / 768.f) - mean * mean + 1e-5f);
#pragma unroll
    for (int q = 0; q < 12; ++q) {
        int d = lane + 64 * q;
        float zz = xz[(size_t)row * 1536 + 768 + d];
        float sil = zz * sigmoidf_(zz);
        g[(size_t)row * 768 + d] = f2bf(((v[q] - mean) * rstd * onw[d] + onb[d]) * sil);
    }
}

extern "C" void kernel_launch(void* const* d_in, const int* in_sizes, int n_in,
                              void* d_out, int out_size, void* d_ws, size_t ws_size,
                              hipStream_t stream) {
    const float* x    = (const float*)d_in[0];
    const float* skip = (const float*)d_in[1];
    const float* pew  = (const float*)d_in[2];
    const float* pnw  = (const float*)d_in[3];
    const float* pnb  = (const float*)d_in[4];
    const float* lpw  = (const float*)d_in[5];
    const float* lpb  = (const float*)d_in[6];
    const float* blw  = (const float*)d_in[7];
    const float* blb  = (const float*)d_in[8];
    const float* inw  = (const float*)d_in[9];
    const float* cw   = (const float*)d_in[10];
    const float* cb   = (const float*)d_in[11];
    const float* xpw  = (const float*)d_in[12];
    const float* dtw  = (const float*)d_in[13];
    const float* dtbi = (const float*)d_in[14];
    const float* alog = (const float*)d_in[15];
    const float* ds   = (const float*)d_in[16];
    const float* onw  = (const float*)d_in[17];
    const float* onb  = (const float*)d_in[18];
    const float* ow   = (const float*)d_in[19];
    float* out = (float*)d_out;

    char* base = (char*)d_ws;
    auto alloc = [&](size_t bytes) -> char* {
        char* p = base;
        base += (bytes + 255) & ~(size_t)255;
        return p;
    };
    float*  xh    = (float*)alloc(2048 * 384 * 4);
    ushort* hbuf  = (ushort*)alloc(2048 * 768 * 2);
    float*  xz    = (float*)alloc((size_t)2048 * 1536 * 4);
    ushort* xcb   = (ushort*)alloc(2048 * 768 * 2);
    ushort* xcwh  = (ushort*)alloc(2048 * 768 * 2);
    float*  dblBC = (float*)alloc(8192 * 32 * 4);
    ushort* dtrb  = (ushort*)alloc((size_t)4 * 2048 * 32 * 2);
    ushort* dtsp  = (ushort*)alloc((size_t)4 * 2048 * 768 * 2);
    ushort* dtscan= (ushort*)alloc((size_t)4 * 2048 * 768 * 2);
    ushort* y4b   = (ushort*)alloc((size_t)8192 * 768 * 2);
    float*  Pg    = (float*)alloc((size_t)8 * 32 * 12288 * 4);
    float*  Hg    = (float*)alloc((size_t)8 * 32 * 12288 * 4);
    float*  H0g   = (float*)alloc((size_t)8 * 32 * 12288 * 4);
    ushort* xspe  = (ushort*)alloc(512 * 768 * 2);
    float*  t1    = (float*)alloc(512 * 1536 * 4);
    ushort* wpe   = (ushort*)alloc((size_t)1536 * 768 * 2);
    ushort* wlp   = (ushort*)alloc(384 * 768 * 2);
    ushort* winb  = (ushort*)alloc((size_t)2 * 1536 * 384 * 2);
    ushort* wob   = (ushort*)alloc((size_t)2 * 384 * 768 * 2);
    ushort* wxpp  = (ushort*)alloc((size_t)2 * 256 * 768 * 2);
    ushort* wdtp  = (ushort*)alloc((size_t)2 * 4 * 768 * 32 * 2);

    cvt_all_k<<<3744, 256, 0, stream>>>(pew, lpw, inw, ow, xpw, dtw,
                                        wpe, wlp, winb, wob, wxpp, wdtp);

    // ---- Stage A ----
    tr_x_k<<<dim3(8, 24, 2), 256, 0, stream>>>(x, xspe);
    gemm_t<64><<<dim3(24, 4), 256, 0, stream>>>(xspe, wpe, nullptr, nullptr, t1,
                                                nullptr, nullptr, nullptr,
                                                512, 1536, 768, 0, 0, 0, 0, 0);
    peskip_k<<<1280, 256, 0, stream>>>(t1, pnw, pnb, skip, hbuf);
    gemm_t<64><<<dim3(6, 16), 256, 0, stream>>>(hbuf, wlp, lpb, nullptr, xh,
                                                nullptr, nullptr, nullptr,
                                                2048, 384, 768, 0, 0, 0, 0, 0);

    // ---- 2 VSS blocks ----
    for (int blk = 0; blk < 2; ++blk) {
        const ushort* inw_i = winb + (size_t)blk * 1536 * 384;
        const float*  cw_i  = cw + (size_t)blk * 768 * 9;
        const float*  cb_i  = cb + (size_t)blk * 768;
        const ushort* xpw_i = wxpp + (size_t)blk * 256 * 768;
        const ushort* dtw_i = wdtp + (size_t)blk * 4 * 768 * 32;
        const float*  dtb_i = dtbi + (size_t)blk * 4 * 768;
        const float*  al_i  = alog + (size_t)blk * 4 * 768 * 16;
        const float*  ds_i  = ds + (size_t)blk * 4 * 768;
        const float*  onw_i = onw + (size_t)blk * 768;
        const float*  onb_i = onb + (size_t)blk * 768;
        const ushort* ow_i  = wob + (size_t)blk * 384 * 768;

        ln_rows_384<<<512, 256, 0, stream>>>(xh, blw + blk * 384, blb + blk * 384,
                                             hbuf);
        gemm_t<128><<<dim3(12, 16), 256, 0, stream>>>(hbuf, inw_i, nullptr,
                                                      nullptr, xz, nullptr,
                                                      nullptr, nullptr,
                                                      2048, 1536, 384,
                                                      0, 0, 0, 0, 0);
        conv_silu_k<<<2048, 256, 0, stream>>>(xz, cw_i, cb_i, xcb, xcwh);
        gemm_t<64><<<dim3(4, 16), 256, 0, stream>>>(xcb, xpw_i, nullptr, nullptr,
                                                    nullptr, nullptr, dblBC, dtrb,
                                                    2048, 256, 768, 0, 0, 0, 0, 2);
        gemm_t<128><<<dim3(6, 16, 4), 256, 0, stream>>>(dtrb, dtw_i, dtb_i,
                                                        nullptr, nullptr, dtsp,
                                                        nullptr, nullptr,
                                                        2048, 768, 32,
                                                        2048 * 32, 768 * 32, 768,
                                                        (long)2048 * 768, 1);
        dt_perm_k<<<4096, 256, 0, stream>>>(dtsp, dtscan);
        scan_p1<<<dim3(12, 31, 8), 64, 0, stream>>>(dtscan, dblBC, xcb, xcwh,
                                                    al_i, Pg, Hg);
        comb_k<<<384, 256, 0, stream>>>(Pg, Hg, H0g);
        scan_p2<<<dim3(12, 32, 8), 64, 0, stream>>>(dtscan, dblBC, xcb, xcwh,
                                                    al_i, H0g, y4b);
        fuse_out_k<<<512, 256, 0, stream>>>(y4b, xcb, xz, ds_i, onw_i, onb_i,
                                            hbuf);
        gemm_t<64><<<dim3(6, 16), 256, 0, stream>>>(hbuf, ow_i, nullptr, xh, xh,
                                                    nullptr, nullptr, nullptr,
                                                    2048, 384, 768, 0, 0, 0, 0, 0);
    }

    tr_out_k<<<dim3(32, 12, 2), 256, 0, stream>>>(xh, out);
}

// Round 9
// 404.658 us; speedup vs baseline: 1.5408x; 1.1480x over previous
//
#include <hip/hip_runtime.h>
#include <math.h>

// Problem constants: B=2, H=W=32 (after expand), L=1024, out_dim=384, Di=768,
// K=4 directions, N=16 state, R=24, depth=2. fp32 in/out; bf16 MFMA GEMMs.

typedef __attribute__((ext_vector_type(8))) short s8v;   // 8 bf16 = 4 VGPRs
typedef __attribute__((ext_vector_type(4))) float f4v;

static __device__ __forceinline__ float sigmoidf_(float x) {
    return 1.f / (1.f + __expf(-x));
}
static __device__ __forceinline__ ushort f2bf(float x) {
    unsigned u = __float_as_uint(x);
    return (ushort)((u + 0x7fff + ((u >> 16) & 1)) >> 16);   // RNE
}
static __device__ __forceinline__ float bf2f(ushort u) {
    return __uint_as_float(((unsigned)u) << 16);
}

// Scan-order <-> spatial-position map. Involution for all k.
static __device__ __forceinline__ int scan_pos(int k, int l) {
    int m = (k & 2) ? (1023 - l) : l;
    return (k & 1) ? (((m & 31) << 5) | (m >> 5)) : m;
}

// ---------------- all weight conversions fp32->bf16 in ONE kernel ----------------
__global__ __launch_bounds__(256) void cvt_all_k(
    const float* __restrict__ pew, const float* __restrict__ lpw,
    const float* __restrict__ inw, const float* __restrict__ ow,
    const float* __restrict__ xpw, const float* __restrict__ dtw,
    ushort* __restrict__ wpe, ushort* __restrict__ wlp,
    ushort* __restrict__ winb, ushort* __restrict__ wob,
    ushort* __restrict__ wxpp, ushort* __restrict__ wdtp) {
    int g = blockIdx.x * 256 + threadIdx.x;
    if (g < 811008) {
        const float* s; ushort* d; int off;
        if (g < 294912)      { s = pew;  d = wpe;  off = g; }
        else if (g < 368640) { s = lpw;  d = wlp;  off = g - 294912; }
        else if (g < 663552) { s = inw;  d = winb; off = g - 368640; }
        else                 { s = ow;   d = wob;  off = g - 663552; }
        float4 v = ((const float4*)s)[off];
        ushort4 o = {f2bf(v.x), f2bf(v.y), f2bf(v.z), f2bf(v.w)};
        ((ushort4*)d)[off] = o;
    } else if (g < 909312) {
        int e = g - 811008;
        int blkb = e / 49152, rem = e % 49152;
        int n = rem / 192, q = rem % 192;
        int k = n >> 6, c = n & 63;
        ushort4 o = {0, 0, 0, 0};
        if (c < 56) {
            float4 v = *(const float4*)(xpw +
                ((size_t)((blkb * 4 + k) * 56 + c)) * 768 + q * 4);
            o = {f2bf(v.x), f2bf(v.y), f2bf(v.z), f2bf(v.w)};
        }
        ((ushort4*)wxpp)[e] = o;
    } else {
        int e = g - 909312;          // 49152 groups
        int rowk = e >> 3, q = e & 7;
        ushort4 o = {0, 0, 0, 0};
        if (q < 6) {
            float4 v = *(const float4*)(dtw + (size_t)rowk * 24 + q * 4);
            o = {f2bf(v.x), f2bf(v.y), f2bf(v.z), f2bf(v.w)};
        }
        ((ushort4*)wdtp)[e] = o;
    }
}

// ---------------- tiled transpose: x (B,768,256) -> (B*256,768) bf16 -------------
__global__ __launch_bounds__(256) void tr_x_k(const float* __restrict__ x,
                                              ushort* __restrict__ o) {
    __shared__ float tile[32][33];
    int b = blockIdx.z, c0 = blockIdx.y * 32, s0 = blockIdx.x * 32;
    int tx = threadIdx.x & 31, ty = threadIdx.x >> 5;
    for (int i = ty; i < 32; i += 8)
        tile[i][tx] = x[((size_t)(b * 768 + c0 + i)) * 256 + s0 + tx];
    __syncthreads();
    for (int i = ty; i < 32; i += 8)
        o[((size_t)(b * 256 + s0 + i)) * 768 + c0 + tx] = f2bf(tile[tx][i]);
}

// ---------------- merged: pe_ln (blocks 0..511) + tr_skip (blocks 512..1279) -----
__global__ __launch_bounds__(256) void peskip_k(const float* __restrict__ t1,
                                                const float* __restrict__ pnw,
                                                const float* __restrict__ pnb,
                                                const float* __restrict__ skip,
                                                ushort* __restrict__ cin) {
    __shared__ float tile[32][33];
    int bx = blockIdx.x;
    if (bx < 512) {
        int w = threadIdx.x >> 6, lane = threadIdx.x & 63;
        int row = bx * 4 + w;
        int b = row >> 10, p = row & 1023;
        int r = p >> 5, col = p & 31;
        int i = r >> 1, a = r & 1, j = col >> 1, b2 = col & 1;
        const float* src =
            t1 + ((size_t)(b * 256 + i * 16 + j)) * 1536 + (a * 2 + b2) * 384;
        float v[6], s1 = 0.f, s2 = 0.f;
#pragma unroll
        for (int q = 0; q < 6; ++q) {
            v[q] = src[lane + 64 * q];
            s1 += v[q]; s2 += v[q] * v[q];
        }
#pragma unroll
        for (int m = 1; m < 64; m <<= 1) {
            s1 += __shfl_xor(s1, m); s2 += __shfl_xor(s2, m);
        }
        float mean = s1 * (1.f / 384.f);
        float rstd = rsqrtf(s2 * (1.f / 384.f) - mean * mean + 1e-5f);
        ushort* o = cin + (size_t)row * 768;
#pragma unroll
        for (int q = 0; q < 6; ++q) {
            int c = lane + 64 * q;
            o[c] = f2bf((v[q] - mean) * rstd * pnw[c] + pnb[c]);
        }
    } else {
        int idx = bx - 512;                 // 768 blocks: b (2) x c0 (12) x s0 (32)
        int b = idx / 384, rem = idx % 384;
        int c0 = (rem / 32) * 32, s0 = (rem % 32) * 32;
        int tx = threadIdx.x & 31, ty = threadIdx.x >> 5;
        for (int i = ty; i < 32; i += 8)
            tile[i][tx] = skip[((size_t)(b * 384 + c0 + i)) * 1024 + s0 + tx];
        __syncthreads();
        for (int i = ty; i < 32; i += 8)
            cin[((size_t)(b * 1024 + s0 + i)) * 768 + 384 + c0 + tx] =
                f2bf(tile[tx][i]);
    }
}

// ---------------- tiled transpose: xh (B*1024,384) -> out (B,384,1024) fp32 ------
__global__ __launch_bounds__(256) void tr_out_k(const float* __restrict__ xh,
                                                float* __restrict__ out) {
    __shared__ float tile[32][33];
    int b = blockIdx.z, p0 = blockIdx.x * 32, c0 = blockIdx.y * 32;
    int tx = threadIdx.x & 31, ty = threadIdx.x >> 5;
    for (int i = ty; i < 32; i += 8)
        tile[i][tx] = xh[((size_t)(b * 1024 + p0 + i)) * 384 + c0 + tx];
    __syncthreads();
    for (int i = ty; i < 32; i += 8)
        out[((size_t)(b * 384 + c0 + i)) * 1024 + p0 + tx] = tile[tx][i];
}

// ---------------- bf16 NT MFMA GEMM, 64x64 tile, pipelined -----------------------
// 4 waves in 2x2, each 32x32 via 2x2 MFMA 16x16x32 tiles. More blocks per GEMM
// than 128-tiles: these small GEMMs are latency-bound (R5: 1 blk/CU, 44us @1%
// MfmaUtil), so CU coverage beats per-block MFMA amortization.
// mode 0: Cf = acc (+bias)(+res) fp32
// mode 1: Cb = bf16(softplus(acc+bias)) contiguous   [dt-proj, z=k]
// mode 2: xproj scatter: dtrb bf16 + dblBC fp32 scan-order
// mode 3: Cb = bf16(acc) contiguous                  [in_proj -> xz bf16]
__global__ __launch_bounds__(256) void gemm64(const ushort* __restrict__ A,
                                              const ushort* __restrict__ B,
                                              const float* __restrict__ bias,
                                              const float* __restrict__ res,
                                              float* __restrict__ Cf,
                                              ushort* __restrict__ Cb,
                                              float* __restrict__ dblBC,
                                              ushort* __restrict__ dtrb,
                                              int M, int N, int K,
                                              long sAz, long sBz, long sBiz,
                                              long sCz, int mode) {
    __shared__ ushort Als[2][64][40];   // 80 B rows: 20-bank stride, 2-way free
    __shared__ ushort Bls[2][64][40];
    A += (size_t)blockIdx.z * sAz;
    B += (size_t)blockIdx.z * sBz;
    if (Cf) Cf += (size_t)blockIdx.z * sCz;
    if (Cb) Cb += (size_t)blockIdx.z * sCz;
    if (bias) bias += (size_t)blockIdx.z * sBiz;
    int t = threadIdx.x;
    int bm = blockIdx.y * 64, bn = blockIdx.x * 64;
    int lane = t & 63, w = t >> 6;
    int wm = (w & 1) * 32, wn = (w >> 1) * 32;
    int r16 = lane & 15, quad = lane >> 4;
    int srow = t >> 2, sq = (t & 3) * 8;   // staging: 4 threads/row, 16 B each
    f4v acc[2][2] = {};
    const ushort* Ag = A + (size_t)(bm + srow) * K + sq;
    const ushort* Bg = B + (size_t)(bn + srow) * K + sq;
    int nt = K >> 5;
    uint4 a0 = *(const uint4*)(Ag);
    uint4 b0 = *(const uint4*)(Bg);
    *(uint4*)&Als[0][srow][sq] = a0;
    *(uint4*)&Bls[0][srow][sq] = b0;
    for (int it = 0; it < nt; ++it) {
        int buf = it & 1;
        __syncthreads();                  // LDS[buf] ready; prev reads of buf^1 done
        if (it + 1 < nt) {                // issue next tile's loads (awaited below)
            int k0 = (it + 1) << 5;
            a0 = *(const uint4*)(Ag + k0);
            b0 = *(const uint4*)(Bg + k0);
        }
        s8v af[2], bfr[2];
#pragma unroll
        for (int i = 0; i < 2; ++i)
            af[i] = *(const s8v*)&Als[buf][wm + i * 16 + r16][quad * 8];
#pragma unroll
        for (int j = 0; j < 2; ++j)
            bfr[j] = *(const s8v*)&Bls[buf][wn + j * 16 + r16][quad * 8];
#pragma unroll
        for (int i = 0; i < 2; ++i)
#pragma unroll
            for (int j = 0; j < 2; ++j)
                acc[i][j] = __builtin_amdgcn_mfma_f32_16x16x32_bf16(
                    af[i], bfr[j], acc[i][j], 0, 0, 0);
        if (it + 1 < nt) {                // vmcnt wait lands here, after MFMAs
            *(uint4*)&Als[buf ^ 1][srow][sq] = a0;
            *(uint4*)&Bls[buf ^ 1][srow][sq] = b0;
        }
    }
    // D mapping: col=lane&15, row=quad*4+reg (m89-verified)
#pragma unroll
    for (int i = 0; i < 2; ++i) {
        int row0 = bm + wm + i * 16 + quad * 4;
#pragma unroll
        for (int j = 0; j < 2; ++j) {
            int col = bn + wn + j * 16 + r16;
            float bv = bias ? bias[col] : 0.f;
#pragma unroll
            for (int r = 0; r < 2 * 2; ++r) {
                // r unrolled 0..3
            }
#pragma unroll
            for (int r = 0; r < 4; ++r) {
                int row = row0 + r;
                float v = acc[i][j][r] + bv;
                if (mode == 0) {
                    if (res) v += res[(size_t)row * N + col];
                    Cf[(size_t)row * N + col] = v;
                } else if (mode == 1) {
                    v = (v > 20.f) ? v : __logf(1.f + __expf(v));
                    Cb[(size_t)row * N + col] = f2bf(v);
                } else if (mode == 3) {
                    Cb[(size_t)row * N + col] = f2bf(v);
                } else {
                    int k = col >> 6, c = col & 63;
                    int b = row >> 10, p = row & 1023;
                    if (c < 32)
                        dtrb[((size_t)k * 2048 + row) * 32 + c] =
                            f2bf((c < 24) ? v : 0.f);
                    if (c >= 24 && c < 56) {
                        int l = scan_pos(k, p);
                        dblBC[(((size_t)(b * 4 + k)) * 1024 + l) * 32 + (c - 24)] = v;
                    }
                }
            }
        }
    }
}

// ---- dt row-permute: dtsp [k][b*1024+p][768] -> dtscan [(k*2+b)*1024+l][768] ----
__global__ __launch_bounds__(256) void dt_perm_k(const ushort* __restrict__ dtsp,
                                                 ushort* __restrict__ dtscan) {
    int r = blockIdx.x * 2 + (threadIdx.x >> 7);   // 8192 rows, grid 4096
    int t = threadIdx.x & 127;
    int l = r & 1023;
    int kb2 = r >> 10;                 // k*2 + b
    int k = kb2 >> 1, b = kb2 & 1;
    int p = scan_pos(k, l);
    const uint* s = (const uint*)(dtsp + ((size_t)(k * 2048 + b * 1024 + p)) * 768);
    uint* d = (uint*)(dtscan + (size_t)r * 768);
    d[t] = s[t];
    d[t + 128] = s[t + 128];
    d[t + 256] = s[t + 256];
}

// ---------------- row LayerNorm over 384 cols -> bf16 (wave/row) ----------------
__global__ __launch_bounds__(256) void ln_rows_384(const float* __restrict__ in,
                                                   const float* __restrict__ wgt,
                                                   const float* __restrict__ bb,
                                                   ushort* __restrict__ out) {
    int w = threadIdx.x >> 6, lane = threadIdx.x & 63;
    int row = blockIdx.x * 4 + w;      // grid 512
    const float* x = in + (size_t)row * 384;
    float v[6], s1 = 0.f, s2 = 0.f;
#pragma unroll
    for (int q = 0; q < 6; ++q) {
        v[q] = x[lane + 64 * q];
        s1 += v[q]; s2 += v[q] * v[q];
    }
#pragma unroll
    for (int m = 1; m < 64; m <<= 1) {
        s1 += __shfl_xor(s1, m); s2 += __shfl_xor(s2, m);
    }
    float mean = s1 * (1.f / 384.f);
    float rstd = rsqrtf(s2 * (1.f / 384.f) - mean * mean + 1e-5f);
#pragma unroll
    for (int q = 0; q < 6; ++q) {
        int c = lane + 64 * q;
        out[(size_t)row * 384 + c] = f2bf((v[q] - mean) * rstd * wgt[c] + bb[c]);
    }
}

// ------- depthwise 3x3 conv + bias + SiLU (bf16 in) -> xcb + xcwh (transposed) ---
__global__ __launch_bounds__(256) void conv_silu_k(const ushort* __restrict__ xzb,
                                                   const float* __restrict__ cw,
                                                   const float* __restrict__ cb,
                                                   ushort* __restrict__ xcb,
                                                   ushort* __restrict__ xcwh) {
    int row = blockIdx.x;
    int b = row >> 10, p = row & 1023;
    int r = p >> 5, col = p & 31;
    int mwh = ((p & 31) << 5) | (p >> 5);
    for (int d = threadIdx.x; d < 768; d += 256) {
        float acc = cb[d];
#pragma unroll
        for (int dy = 0; dy < 3; ++dy) {
            int rr = r + dy - 1;
            if ((unsigned)rr > 31u) continue;
#pragma unroll
            for (int dx = 0; dx < 3; ++dx) {
                int cc = col + dx - 1;
                if ((unsigned)cc > 31u) continue;
                acc += cw[d * 9 + dy * 3 + dx] *
                       bf2f(xzb[((size_t)(b * 1024 + rr * 32 + cc)) * 1536 + d]);
            }
        }
        float o = acc * sigmoidf_(acc);
        ushort ob = f2bf(o);
        xcb[(size_t)row * 768 + d] = ob;
        xcwh[((size_t)(b * 1024 + mwh)) * 768 + d] = ob;
    }
}

// ======== selective scan: fully sequential IO (scan-order layouts) ========
// dtscan bf16 [(k*2+b)*1024+l][768]; u: xcb (k even) / xcwh (k odd), row l or
// 1023-l (k>=2); dblBC fp32 scan-order; y4b written in scan order.
// Chunks: 32 x 32 steps. Pg/Hg/H0g: [(kb*32+ch)*12288 + d*16 + n].

__global__ __launch_bounds__(64) void scan_p1(const ushort* __restrict__ dtscan,
                                              const float* __restrict__ dblBC,
                                              const ushort* __restrict__ xcb,
                                              const ushort* __restrict__ xcwh,
                                              const float* __restrict__ alog,
                                              float* __restrict__ Pg,
                                              float* __restrict__ Hg) {
    __shared__ float sB[32][16];
    int lane = threadIdx.x;
    int d0 = blockIdx.x * 64, ch = blockIdx.y, kb = blockIdx.z;
    int k = kb & 3, b = kb >> 2;
    int d = d0 + lane;
    float A2[16];
    {
        const float4* ap = (const float4*)(alog + ((size_t)(k * 768 + d)) * 16);
#pragma unroll
        for (int q = 0; q < 4; ++q) {
            float4 v = ap[q];
            A2[4 * q + 0] = -__expf(v.x) * 1.44269504f;
            A2[4 * q + 1] = -__expf(v.y) * 1.44269504f;
            A2[4 * q + 2] = -__expf(v.z) * 1.44269504f;
            A2[4 * q + 3] = -__expf(v.w) * 1.44269504f;
        }
    }
    int l0 = ch * 32;
    const ushort* dts = dtscan + ((size_t)((k * 2 + b) * 1024 + l0)) * 768 + d;
    const ushort* ub = ((k & 1) ? xcwh : xcb) + (size_t)b * 786432 + d;
    const float* bcp = dblBC + (size_t)kb * 1024 * 32;
    float rdt[32], ru[32], rB[8];
#pragma unroll
    for (int i = 0; i < 32; ++i) rdt[i] = bf2f(dts[(size_t)i * 768]);
    if (k & 2) {
#pragma unroll
        for (int i = 0; i < 32; ++i)
            ru[i] = bf2f(ub[(size_t)(1023 - (l0 + i)) * 768]);
    } else {
#pragma unroll
        for (int i = 0; i < 32; ++i) ru[i] = bf2f(ub[(size_t)(l0 + i) * 768]);
    }
    int bi = lane >> 4, bn_ = lane & 15;
#pragma unroll
    for (int j = 0; j < 8; ++j)
        rB[j] = bcp[(size_t)(l0 + bi + 4 * j) * 32 + bn_];
#pragma unroll
    for (int j = 0; j < 8; ++j) sB[bi + 4 * j][bn_] = rB[j];
    __syncthreads();
    float h[16], P[16];
#pragma unroll
    for (int n = 0; n < 16; ++n) { h[n] = 0.f; P[n] = 1.f; }
#pragma unroll 4
    for (int i = 0; i < 32; ++i) {
        float dtv = rdt[i], dtu = dtv * ru[i];
        const float4* B4 = (const float4*)&sB[i][0];
        float4 q0 = B4[0], q1 = B4[1], q2 = B4[2], q3 = B4[3];
        float Bv[16] = {q0.x, q0.y, q0.z, q0.w, q1.x, q1.y, q1.z, q1.w,
                        q2.x, q2.y, q2.z, q2.w, q3.x, q3.y, q3.z, q3.w};
#pragma unroll
        for (int n = 0; n < 16; ++n) {
            float a = __builtin_amdgcn_exp2f(dtv * A2[n]);
            P[n] *= a;
            h[n] = a * h[n] + dtu * Bv[n];
        }
    }
    float* pp = Pg + ((size_t)(kb * 32 + ch)) * 12288 + d * 16;
    float* hp = Hg + ((size_t)(kb * 32 + ch)) * 12288 + d * 16;
#pragma unroll
    for (int q = 0; q < 4; ++q) {
        float4 pv = {P[4 * q], P[4 * q + 1], P[4 * q + 2], P[4 * q + 3]};
        float4 hv = {h[4 * q], h[4 * q + 1], h[4 * q + 2], h[4 * q + 3]};
        *(float4*)(pp + 4 * q) = pv;
        *(float4*)(hp + 4 * q) = hv;
    }
}

// prefix fold: h0[ch] for all chains. 8 kb * 12288 threads, unrolled over 31.
__global__ __launch_bounds__(256) void comb_k(const float* __restrict__ Pg,
                                              const float* __restrict__ Hg,
                                              float* __restrict__ H0g) {
    int t = blockIdx.x * 256 + threadIdx.x;   // 98304
    int kb = t / 12288, dn = t % 12288;
    size_t base = (size_t)kb * 32 * 12288 + dn;
    float pv[31], hv[31];
#pragma unroll
    for (int ch = 0; ch < 31; ++ch) {
        pv[ch] = Pg[base + (size_t)ch * 12288];
        hv[ch] = Hg[base + (size_t)ch * 12288];
    }
    float h = 0.f;
    H0g[base] = 0.f;
#pragma unroll
    for (int ch = 0; ch < 31; ++ch) {
        h = pv[ch] * h + hv[ch];
        H0g[base + (size_t)(ch + 1) * 12288] = h;
    }
}

__global__ __launch_bounds__(64) void scan_p2(const ushort* __restrict__ dtscan,
                                              const float* __restrict__ dblBC,
                                              const ushort* __restrict__ xcb,
                                              const ushort* __restrict__ xcwh,
                                              const float* __restrict__ alog,
                                              const float* __restrict__ H0g,
                                              ushort* __restrict__ y4b) {
    __shared__ float sB[32][16];
    __shared__ float sC[32][16];
    int lane = threadIdx.x;
    int d0 = blockIdx.x * 64, ch = blockIdx.y, kb = blockIdx.z;
    int k = kb & 3, b = kb >> 2;
    int d = d0 + lane;
    float A2[16];
    {
        const float4* ap = (const float4*)(alog + ((size_t)(k * 768 + d)) * 16);
#pragma unroll
        for (int q = 0; q < 4; ++q) {
            float4 v = ap[q];
            A2[4 * q + 0] = -__expf(v.x) * 1.44269504f;
            A2[4 * q + 1] = -__expf(v.y) * 1.44269504f;
            A2[4 * q + 2] = -__expf(v.z) * 1.44269504f;
            A2[4 * q + 3] = -__expf(v.w) * 1.44269504f;
        }
    }
    float h[16];
    {
        const float4* h0p =
            (const float4*)(H0g + ((size_t)(kb * 32 + ch)) * 12288 + d * 16);
#pragma unroll
        for (int q = 0; q < 4; ++q) {
            float4 hv = h0p[q];
            h[4 * q + 0] = hv.x; h[4 * q + 1] = hv.y;
            h[4 * q + 2] = hv.z; h[4 * q + 3] = hv.w;
        }
    }
    int l0 = ch * 32;
    const ushort* dts = dtscan + ((size_t)((k * 2 + b) * 1024 + l0)) * 768 + d;
    const ushort* ub = ((k & 1) ? xcwh : xcb) + (size_t)b * 786432 + d;
    const float* bcp = dblBC + (size_t)kb * 1024 * 32;
    ushort* yp = y4b + ((size_t)(kb * 1024 + l0)) * 768 + d;
    float rdt[32], ru[32], rB[8], rC[8];
#pragma unroll
    for (int i = 0; i < 32; ++i) rdt[i] = bf2f(dts[(size_t)i * 768]);
    if (k & 2) {
#pragma unroll
        for (int i = 0; i < 32; ++i)
            ru[i] = bf2f(ub[(size_t)(1023 - (l0 + i)) * 768]);
    } else {
#pragma unroll
        for (int i = 0; i < 32; ++i) ru[i] = bf2f(ub[(size_t)(l0 + i) * 768]);
    }
    int bi = lane >> 4, bn_ = lane & 15;
#pragma unroll
    for (int j = 0; j < 8; ++j) {
        rB[j] = bcp[(size_t)(l0 + bi + 4 * j) * 32 + bn_];
        rC[j] = bcp[(size_t)(l0 + bi + 4 * j) * 32 + 16 + bn_];
    }
#pragma unroll
    for (int j = 0; j < 8; ++j) {
        sB[bi + 4 * j][bn_] = rB[j];
        sC[bi + 4 * j][bn_] = rC[j];
    }
    __syncthreads();
#pragma unroll 4
    for (int i = 0; i < 32; ++i) {
        float dtv = rdt[i], dtu = dtv * ru[i];
        const float4* B4 = (const float4*)&sB[i][0];
        const float4* C4 = (const float4*)&sC[i][0];
        float4 q0 = B4[0], q1 = B4[1], q2 = B4[2], q3 = B4[3];
        float Bv[16] = {q0.x, q0.y, q0.z, q0.w, q1.x, q1.y, q1.z, q1.w,
                        q2.x, q2.y, q2.z, q2.w, q3.x, q3.y, q3.z, q3.w};
        float4 c0 = C4[0], c1 = C4[1], c2 = C4[2], c3 = C4[3];
        float Cv[16] = {c0.x, c0.y, c0.z, c0.w, c1.x, c1.y, c1.z, c1.w,
                        c2.x, c2.y, c2.z, c2.w, c3.x, c3.y, c3.z, c3.w};
        float y = 0.f;
#pragma unroll
        for (int n = 0; n < 16; ++n) {
            float a = __builtin_amdgcn_exp2f(dtv * A2[n]);
            h[n] = a * h[n] + dtu * Bv[n];
            y += h[n] * Cv[n];
        }
        yp[(size_t)i * 768] = f2bf(y);
    }
}

// ------- sum 4 dirs (row-gather from scan order) + D*u, out-LN, *silu(z) ---------
__global__ __launch_bounds__(256) void fuse_out_k(const ushort* __restrict__ y4b,
                                                  const ushort* __restrict__ xcb,
                                                  const ushort* __restrict__ xzb,
                                                  const float* __restrict__ ds,
                                                  const float* __restrict__ onw,
                                                  const float* __restrict__ onb,
                                                  ushort* __restrict__ g) {
    int w = threadIdx.x >> 6, lane = threadIdx.x & 63;
    int row = blockIdx.x * 4 + w;      // grid 512
    int b = row >> 10, p = row & 1023;
    int l0 = scan_pos(0, p), l1 = scan_pos(1, p);
    int l2 = scan_pos(2, p), l3 = scan_pos(3, p);
    const ushort* y0 = y4b + ((size_t)((b * 4 + 0) * 1024 + l0)) * 768;
    const ushort* y1 = y4b + ((size_t)((b * 4 + 1) * 1024 + l1)) * 768;
    const ushort* y2 = y4b + ((size_t)((b * 4 + 2) * 1024 + l2)) * 768;
    const ushort* y3 = y4b + ((size_t)((b * 4 + 3) * 1024 + l3)) * 768;
    float v[12], s1 = 0.f, s2 = 0.f;
#pragma unroll
    for (int q = 0; q < 12; ++q) {
        int d = lane + 64 * q;
        float u = bf2f(xcb[(size_t)row * 768 + d]);
        float dsum = ds[d] + ds[768 + d] + ds[1536 + d] + ds[2304 + d];
        float val = dsum * u + bf2f(y0[d]) + bf2f(y1[d]) + bf2f(y2[d]) + bf2f(y3[d]);
        v[q] = val; s1 += val; s2 += val * val;
    }
#pragma unroll
    for (int m = 1; m < 64; m <<= 1) {
        s1 += __shfl_xor(s1, m); s2 += __shfl_xor(s2, m);
    }
    float mean = s1 * (1.f / 768.f);
    float rstd = rsqrtf(s2 * (1.f / 768.f) - mean * mean + 1e-5f);
#pragma unroll
    for (int q = 0; q < 12; ++q) {
        int d = lane + 64 * q;
        float zz = bf2f(xzb[(size_t)row * 1536 + 768 + d]);
        float sil = zz * sigmoidf_(zz);
        g[(size_t)row * 768 + d] = f2bf(((v[q] - mean) * rstd * onw[d] + onb[d]) * sil);
    }
}

extern "C" void kernel_launch(void* const* d_in, const int* in_sizes, int n_in,
                              void* d_out, int out_size, void* d_ws, size_t ws_size,
                              hipStream_t stream) {
    const float* x    = (const float*)d_in[0];
    const float* skip = (const float*)d_in[1];
    const float* pew  = (const float*)d_in[2];
    const float* pnw  = (const float*)d_in[3];
    const float* pnb  = (const float*)d_in[4];
    const float* lpw  = (const float*)d_in[5];
    const float* lpb  = (const float*)d_in[6];
    const float* blw  = (const float*)d_in[7];
    const float* blb  = (const float*)d_in[8];
    const float* inw  = (const float*)d_in[9];
    const float* cw   = (const float*)d_in[10];
    const float* cb   = (const float*)d_in[11];
    const float* xpw  = (const float*)d_in[12];
    const float* dtw  = (const float*)d_in[13];
    const float* dtbi = (const float*)d_in[14];
    const float* alog = (const float*)d_in[15];
    const float* ds   = (const float*)d_in[16];
    const float* onw  = (const float*)d_in[17];
    const float* onb  = (const float*)d_in[18];
    const float* ow   = (const float*)d_in[19];
    float* out = (float*)d_out;

    char* base = (char*)d_ws;
    auto alloc = [&](size_t bytes) -> char* {
        char* p = base;
        base += (bytes + 255) & ~(size_t)255;
        return p;
    };
    float*  xh    = (float*)alloc(2048 * 384 * 4);
    ushort* hbuf  = (ushort*)alloc(2048 * 768 * 2);
    ushort* xzb   = (ushort*)alloc((size_t)2048 * 1536 * 2);
    ushort* xcb   = (ushort*)alloc(2048 * 768 * 2);
    ushort* xcwh  = (ushort*)alloc(2048 * 768 * 2);
    float*  dblBC = (float*)alloc(8192 * 32 * 4);
    ushort* dtrb  = (ushort*)alloc((size_t)4 * 2048 * 32 * 2);
    ushort* dtsp  = (ushort*)alloc((size_t)4 * 2048 * 768 * 2);
    ushort* dtscan= (ushort*)alloc((size_t)4 * 2048 * 768 * 2);
    ushort* y4b   = (ushort*)alloc((size_t)8192 * 768 * 2);
    float*  Pg    = (float*)alloc((size_t)8 * 32 * 12288 * 4);
    float*  Hg    = (float*)alloc((size_t)8 * 32 * 12288 * 4);
    float*  H0g   = (float*)alloc((size_t)8 * 32 * 12288 * 4);
    ushort* xspe  = (ushort*)alloc(512 * 768 * 2);
    float*  t1    = (float*)alloc(512 * 1536 * 4);
    ushort* wpe   = (ushort*)alloc((size_t)1536 * 768 * 2);
    ushort* wlp   = (ushort*)alloc(384 * 768 * 2);
    ushort* winb  = (ushort*)alloc((size_t)2 * 1536 * 384 * 2);
    ushort* wob   = (ushort*)alloc((size_t)2 * 384 * 768 * 2);
    ushort* wxpp  = (ushort*)alloc((size_t)2 * 256 * 768 * 2);
    ushort* wdtp  = (ushort*)alloc((size_t)2 * 4 * 768 * 32 * 2);

    cvt_all_k<<<3744, 256, 0, stream>>>(pew, lpw, inw, ow, xpw, dtw,
                                        wpe, wlp, winb, wob, wxpp, wdtp);

    // ---- Stage A ----
    tr_x_k<<<dim3(8, 24, 2), 256, 0, stream>>>(x, xspe);
    gemm64<<<dim3(24, 8), 256, 0, stream>>>(xspe, wpe, nullptr, nullptr, t1,
                                            nullptr, nullptr, nullptr,
                                            512, 1536, 768, 0, 0, 0, 0, 0);
    peskip_k<<<1280, 256, 0, stream>>>(t1, pnw, pnb, skip, hbuf);
    gemm64<<<dim3(6, 32), 256, 0, stream>>>(hbuf, wlp, lpb, nullptr, xh,
                                            nullptr, nullptr, nullptr,
                                            2048, 384, 768, 0, 0, 0, 0, 0);

    // ---- 2 VSS blocks ----
    for (int blk = 0; blk < 2; ++blk) {
        const ushort* inw_i = winb + (size_t)blk * 1536 * 384;
        const float*  cw_i  = cw + (size_t)blk * 768 * 9;
        const float*  cb_i  = cb + (size_t)blk * 768;
        const ushort* xpw_i = wxpp + (size_t)blk * 256 * 768;
        const ushort* dtw_i = wdtp + (size_t)blk * 4 * 768 * 32;
        const float*  dtb_i = dtbi + (size_t)blk * 4 * 768;
        const float*  al_i  = alog + (size_t)blk * 4 * 768 * 16;
        const float*  ds_i  = ds + (size_t)blk * 4 * 768;
        const float*  onw_i = onw + (size_t)blk * 768;
        const float*  onb_i = onb + (size_t)blk * 768;
        const ushort* ow_i  = wob + (size_t)blk * 384 * 768;

        ln_rows_384<<<512, 256, 0, stream>>>(xh, blw + blk * 384, blb + blk * 384,
                                             hbuf);
        gemm64<<<dim3(24, 32), 256, 0, stream>>>(hbuf, inw_i, nullptr, nullptr,
                                                 nullptr, xzb, nullptr, nullptr,
                                                 2048, 1536, 384, 0, 0, 0, 0, 3);
        conv_silu_k<<<2048, 256, 0, stream>>>(xzb, cw_i, cb_i, xcb, xcwh);
        gemm64<<<dim3(4, 32), 256, 0, stream>>>(xcb, xpw_i, nullptr, nullptr,
                                                nullptr, nullptr, dblBC, dtrb,
                                                2048, 256, 768, 0, 0, 0, 0, 2);
        gemm64<<<dim3(12, 32, 4), 256, 0, stream>>>(dtrb, dtw_i, dtb_i, nullptr,
                                                    nullptr, dtsp, nullptr, nullptr,
                                                    2048, 768, 32,
                                                    2048 * 32, 768 * 32, 768,
                                                    (long)2048 * 768, 1);
        dt_perm_k<<<4096, 256, 0, stream>>>(dtsp, dtscan);
        scan_p1<<<dim3(12, 31, 8), 64, 0, stream>>>(dtscan, dblBC, xcb, xcwh,
                                                    al_i, Pg, Hg);
        comb_k<<<384, 256, 0, stream>>>(Pg, Hg, H0g);
        scan_p2<<<dim3(12, 32, 8), 64, 0, stream>>>(dtscan, dblBC, xcb, xcwh,
                                                    al_i, H0g, y4b);
        fuse_out_k<<<512, 256, 0, stream>>>(y4b, xcb, xzb, ds_i, onw_i, onb_i,
                                            hbuf);
        gemm64<<<dim3(6, 32), 256, 0, stream>>>(hbuf, ow_i, nullptr, xh, xh,
                                                nullptr, nullptr, nullptr,
                                                2048, 384, 768, 0, 0, 0, 0, 0);
    }

    tr_out_k<<<dim3(32, 12, 2), 256, 0, stream>>>(xh, out);
}

// Round 10
// 388.934 us; speedup vs baseline: 1.6031x; 1.0404x over previous
//
#include <hip/hip_runtime.h>
#include <math.h>

// Problem constants: B=2, H=W=32 (after expand), L=1024, out_dim=384, Di=768,
// K=4 directions, N=16 state, R=24, depth=2. fp32 in/out; bf16 MFMA GEMMs.

typedef __attribute__((ext_vector_type(8))) short s8v;   // 8 bf16 = 4 VGPRs
typedef __attribute__((ext_vector_type(4))) float f4v;

static __device__ __forceinline__ float sigmoidf_(float x) {
    return 1.f / (1.f + __expf(-x));
}
static __device__ __forceinline__ ushort f2bf(float x) {
    unsigned u = __float_as_uint(x);
    return (ushort)((u + 0x7fff + ((u >> 16) & 1)) >> 16);   // RNE
}
static __device__ __forceinline__ float bf2f(ushort u) {
    return __uint_as_float(((unsigned)u) << 16);
}

// Scan-order <-> spatial-position map. Involution for all k.
static __device__ __forceinline__ int scan_pos(int k, int l) {
    int m = (k & 2) ? (1023 - l) : l;
    return (k & 1) ? (((m & 31) << 5) | (m >> 5)) : m;
}

// ------- weight conversions fp32->bf16 + x transpose, ONE kernel ----------------
// blocks [0,3744): converts; blocks [3744,4128): tiled transpose of x.
__global__ __launch_bounds__(256) void cvt_all_k(
    const float* __restrict__ pew, const float* __restrict__ lpw,
    const float* __restrict__ inw, const float* __restrict__ ow,
    const float* __restrict__ xpw, const float* __restrict__ dtw,
    const float* __restrict__ x,
    ushort* __restrict__ wpe, ushort* __restrict__ wlp,
    ushort* __restrict__ winb, ushort* __restrict__ wob,
    ushort* __restrict__ wxpp, ushort* __restrict__ wdtp,
    ushort* __restrict__ xspe) {
    __shared__ float tile[32][33];
    if (blockIdx.x >= 3744) {
        // transpose x (B,768,256) -> (B*256,768) bf16
        int idx = blockIdx.x - 3744;        // 384 = 8 (s0) x 24 (c0) x 2 (b)
        int b = idx / 192, rem = idx % 192;
        int c0 = (rem / 8) * 32, s0 = (rem % 8) * 32;
        int tx = threadIdx.x & 31, ty = threadIdx.x >> 5;
        for (int i = ty; i < 32; i += 8)
            tile[i][tx] = x[((size_t)(b * 768 + c0 + i)) * 256 + s0 + tx];
        __syncthreads();
        for (int i = ty; i < 32; i += 8)
            xspe[((size_t)(b * 256 + s0 + i)) * 768 + c0 + tx] = f2bf(tile[tx][i]);
        return;
    }
    int g = blockIdx.x * 256 + threadIdx.x;
    if (g < 811008) {
        const float* s; ushort* d; int off;
        if (g < 294912)      { s = pew;  d = wpe;  off = g; }
        else if (g < 368640) { s = lpw;  d = wlp;  off = g - 294912; }
        else if (g < 663552) { s = inw;  d = winb; off = g - 368640; }
        else                 { s = ow;   d = wob;  off = g - 663552; }
        float4 v = ((const float4*)s)[off];
        ushort4 o = {f2bf(v.x), f2bf(v.y), f2bf(v.z), f2bf(v.w)};
        ((ushort4*)d)[off] = o;
    } else if (g < 909312) {
        int e = g - 811008;
        int blkb = e / 49152, rem = e % 49152;
        int n = rem / 192, q = rem % 192;
        int k = n >> 6, c = n & 63;
        ushort4 o = {0, 0, 0, 0};
        if (c < 56) {
            float4 v = *(const float4*)(xpw +
                ((size_t)((blkb * 4 + k) * 56 + c)) * 768 + q * 4);
            o = {f2bf(v.x), f2bf(v.y), f2bf(v.z), f2bf(v.w)};
        }
        ((ushort4*)wxpp)[e] = o;
    } else {
        int e = g - 909312;          // 49152 groups
        int rowk = e >> 3, q = e & 7;
        ushort4 o = {0, 0, 0, 0};
        if (q < 6) {
            float4 v = *(const float4*)(dtw + (size_t)rowk * 24 + q * 4);
            o = {f2bf(v.x), f2bf(v.y), f2bf(v.z), f2bf(v.w)};
        }
        ((ushort4*)wdtp)[e] = o;
    }
}

// ---------------- merged: pe_ln (blocks 0..511) + tr_skip (blocks 512..1279) -----
__global__ __launch_bounds__(256) void peskip_k(const float* __restrict__ t1,
                                                const float* __restrict__ pnw,
                                                const float* __restrict__ pnb,
                                                const float* __restrict__ skip,
                                                ushort* __restrict__ cin) {
    __shared__ float tile[32][33];
    int bx = blockIdx.x;
    if (bx < 512) {
        int w = threadIdx.x >> 6, lane = threadIdx.x & 63;
        int row = bx * 4 + w;
        int b = row >> 10, p = row & 1023;
        int r = p >> 5, col = p & 31;
        int i = r >> 1, a = r & 1, j = col >> 1, b2 = col & 1;
        const float* src =
            t1 + ((size_t)(b * 256 + i * 16 + j)) * 1536 + (a * 2 + b2) * 384;
        float v[6], s1 = 0.f, s2 = 0.f;
#pragma unroll
        for (int q = 0; q < 6; ++q) {
            v[q] = src[lane + 64 * q];
            s1 += v[q]; s2 += v[q] * v[q];
        }
#pragma unroll
        for (int m = 1; m < 64; m <<= 1) {
            s1 += __shfl_xor(s1, m); s2 += __shfl_xor(s2, m);
        }
        float mean = s1 * (1.f / 384.f);
        float rstd = rsqrtf(s2 * (1.f / 384.f) - mean * mean + 1e-5f);
        ushort* o = cin + (size_t)row * 768;
#pragma unroll
        for (int q = 0; q < 6; ++q) {
            int c = lane + 64 * q;
            o[c] = f2bf((v[q] - mean) * rstd * pnw[c] + pnb[c]);
        }
    } else {
        int idx = bx - 512;                 // 768 blocks: b (2) x c0 (12) x s0 (32)
        int b = idx / 384, rem = idx % 384;
        int c0 = (rem / 32) * 32, s0 = (rem % 32) * 32;
        int tx = threadIdx.x & 31, ty = threadIdx.x >> 5;
        for (int i = ty; i < 32; i += 8)
            tile[i][tx] = skip[((size_t)(b * 384 + c0 + i)) * 1024 + s0 + tx];
        __syncthreads();
        for (int i = ty; i < 32; i += 8)
            cin[((size_t)(b * 1024 + s0 + i)) * 768 + 384 + c0 + tx] =
                f2bf(tile[tx][i]);
    }
}

// ---------------- tiled transpose: xh (B*1024,384) -> out (B,384,1024) fp32 ------
__global__ __launch_bounds__(256) void tr_out_k(const float* __restrict__ xh,
                                                float* __restrict__ out) {
    __shared__ float tile[32][33];
    int b = blockIdx.z, p0 = blockIdx.x * 32, c0 = blockIdx.y * 32;
    int tx = threadIdx.x & 31, ty = threadIdx.x >> 5;
    for (int i = ty; i < 32; i += 8)
        tile[i][tx] = xh[((size_t)(b * 1024 + p0 + i)) * 384 + c0 + tx];
    __syncthreads();
    for (int i = ty; i < 32; i += 8)
        out[((size_t)(b * 384 + c0 + i)) * 1024 + p0 + tx] = tile[tx][i];
}

// ---------------- bf16 NT MFMA GEMM, 64x64 tile, pipelined -----------------------
// 4 waves in 2x2, each 32x32 via 2x2 MFMA 16x16x32 tiles (latency regime: CU
// coverage beats per-block amortization — R9 verified).
// mode 0: Cf = acc (+bias)(+res) fp32
// mode 1: Cb = bf16(softplus(acc+bias)) contiguous   [dt-proj, z=k; A rows are
//         already scan-ordered so output IS dtscan — no permute pass]
// mode 2: xproj: dtrb bf16 rows scattered to scan order (64 B rows — dense-row
//         scatter is cheap; R7's 2 B-element scatter was not) + dblBC fp32
// mode 3: Cb = bf16(acc) contiguous                  [in_proj -> xz bf16]
__global__ __launch_bounds__(256) void gemm64(const ushort* __restrict__ A,
                                              const ushort* __restrict__ B,
                                              const float* __restrict__ bias,
                                              const float* __restrict__ res,
                                              float* __restrict__ Cf,
                                              ushort* __restrict__ Cb,
                                              float* __restrict__ dblBC,
                                              ushort* __restrict__ dtrb,
                                              int M, int N, int K,
                                              long sAz, long sBz, long sBiz,
                                              long sCz, int mode) {
    __shared__ ushort Als[2][64][40];   // 80 B rows: 20-bank stride, 2-way free
    __shared__ ushort Bls[2][64][40];
    A += (size_t)blockIdx.z * sAz;
    B += (size_t)blockIdx.z * sBz;
    if (Cf) Cf += (size_t)blockIdx.z * sCz;
    if (Cb) Cb += (size_t)blockIdx.z * sCz;
    if (bias) bias += (size_t)blockIdx.z * sBiz;
    int t = threadIdx.x;
    int bm = blockIdx.y * 64, bn = blockIdx.x * 64;
    int lane = t & 63, w = t >> 6;
    int wm = (w & 1) * 32, wn = (w >> 1) * 32;
    int r16 = lane & 15, quad = lane >> 4;
    int srow = t >> 2, sq = (t & 3) * 8;   // staging: 4 threads/row, 16 B each
    f4v acc[2][2] = {};
    const ushort* Ag = A + (size_t)(bm + srow) * K + sq;
    const ushort* Bg = B + (size_t)(bn + srow) * K + sq;
    int nt = K >> 5;
    uint4 a0 = *(const uint4*)(Ag);
    uint4 b0 = *(const uint4*)(Bg);
    *(uint4*)&Als[0][srow][sq] = a0;
    *(uint4*)&Bls[0][srow][sq] = b0;
    for (int it = 0; it < nt; ++it) {
        int buf = it & 1;
        __syncthreads();                  // LDS[buf] ready; prev reads of buf^1 done
        if (it + 1 < nt) {                // issue next tile's loads (awaited below)
            int k0 = (it + 1) << 5;
            a0 = *(const uint4*)(Ag + k0);
            b0 = *(const uint4*)(Bg + k0);
        }
        s8v af[2], bfr[2];
#pragma unroll
        for (int i = 0; i < 2; ++i)
            af[i] = *(const s8v*)&Als[buf][wm + i * 16 + r16][quad * 8];
#pragma unroll
        for (int j = 0; j < 2; ++j)
            bfr[j] = *(const s8v*)&Bls[buf][wn + j * 16 + r16][quad * 8];
#pragma unroll
        for (int i = 0; i < 2; ++i)
#pragma unroll
            for (int j = 0; j < 2; ++j)
                acc[i][j] = __builtin_amdgcn_mfma_f32_16x16x32_bf16(
                    af[i], bfr[j], acc[i][j], 0, 0, 0);
        if (it + 1 < nt) {                // vmcnt wait lands here, after MFMAs
            *(uint4*)&Als[buf ^ 1][srow][sq] = a0;
            *(uint4*)&Bls[buf ^ 1][srow][sq] = b0;
        }
    }
    // D mapping: col=lane&15, row=quad*4+reg (m89-verified)
#pragma unroll
    for (int i = 0; i < 2; ++i) {
        int row0 = bm + wm + i * 16 + quad * 4;
#pragma unroll
        for (int j = 0; j < 2; ++j) {
            int col = bn + wn + j * 16 + r16;
            float bv = bias ? bias[col] : 0.f;
#pragma unroll
            for (int r = 0; r < 4; ++r) {
                int row = row0 + r;
                float v = acc[i][j][r] + bv;
                if (mode == 0) {
                    if (res) v += res[(size_t)row * N + col];
                    Cf[(size_t)row * N + col] = v;
                } else if (mode == 1) {
                    v = (v > 20.f) ? v : __logf(1.f + __expf(v));
                    Cb[(size_t)row * N + col] = f2bf(v);
                } else if (mode == 3) {
                    Cb[(size_t)row * N + col] = f2bf(v);
                } else {
                    int k = col >> 6, c = col & 63;
                    int b = row >> 10, p = row & 1023;
                    int l = scan_pos(k, p);
                    if (c < 32)
                        dtrb[((size_t)k * 2048 + b * 1024 + l) * 32 + c] =
                            f2bf((c < 24) ? v : 0.f);
                    if (c >= 24 && c < 56) {
                        dblBC[(((size_t)(b * 4 + k)) * 1024 + l) * 32 + (c - 24)] = v;
                    }
                }
            }
        }
    }
}

// ---------------- row LayerNorm over 384 cols -> bf16 (wave/row) ----------------
__global__ __launch_bounds__(256) void ln_rows_384(const float* __restrict__ in,
                                                   const float* __restrict__ wgt,
                                                   const float* __restrict__ bb,
                                                   ushort* __restrict__ out) {
    int w = threadIdx.x >> 6, lane = threadIdx.x & 63;
    int row = blockIdx.x * 4 + w;      // grid 512
    const float* x = in + (size_t)row * 384;
    float v[6], s1 = 0.f, s2 = 0.f;
#pragma unroll
    for (int q = 0; q < 6; ++q) {
        v[q] = x[lane + 64 * q];
        s1 += v[q]; s2 += v[q] * v[q];
    }
#pragma unroll
    for (int m = 1; m < 64; m <<= 1) {
        s1 += __shfl_xor(s1, m); s2 += __shfl_xor(s2, m);
    }
    float mean = s1 * (1.f / 384.f);
    float rstd = rsqrtf(s2 * (1.f / 384.f) - mean * mean + 1e-5f);
#pragma unroll
    for (int q = 0; q < 6; ++q) {
        int c = lane + 64 * q;
        out[(size_t)row * 384 + c] = f2bf((v[q] - mean) * rstd * wgt[c] + bb[c]);
    }
}

// ------- depthwise 3x3 conv + bias + SiLU (bf16 in) -> xcb + xcwh (transposed) ---
__global__ __launch_bounds__(256) void conv_silu_k(const ushort* __restrict__ xzb,
                                                   const float* __restrict__ cw,
                                                   const float* __restrict__ cb,
                                                   ushort* __restrict__ xcb,
                                                   ushort* __restrict__ xcwh) {
    int row = blockIdx.x;
    int b = row >> 10, p = row & 1023;
    int r = p >> 5, col = p & 31;
    int mwh = ((p & 31) << 5) | (p >> 5);
    for (int d = threadIdx.x; d < 768; d += 256) {
        float acc = cb[d];
#pragma unroll
        for (int dy = 0; dy < 3; ++dy) {
            int rr = r + dy - 1;
            if ((unsigned)rr > 31u) continue;
#pragma unroll
            for (int dx = 0; dx < 3; ++dx) {
                int cc = col + dx - 1;
                if ((unsigned)cc > 31u) continue;
                acc += cw[d * 9 + dy * 3 + dx] *
                       bf2f(xzb[((size_t)(b * 1024 + rr * 32 + cc)) * 1536 + d]);
            }
        }
        float o = acc * sigmoidf_(acc);
        ushort ob = f2bf(o);
        xcb[(size_t)row * 768 + d] = ob;
        xcwh[((size_t)(b * 1024 + mwh)) * 768 + d] = ob;
    }
}

// ======== selective scan: fully sequential IO (scan-order layouts) ========
// dtscan bf16 [(k*2+b)*1024+l][768] (written directly by dt-GEMM); u: xcb (k
// even) / xcwh (k odd), row l or 1023-l (k>=2); dblBC fp32 scan-order; y4b
// written in scan order. Chunks: 32 x 32. Pg/Hg/H0g: [(kb*32+ch)*12288+d*16+n].

__global__ __launch_bounds__(64) void scan_p1(const ushort* __restrict__ dtscan,
                                              const float* __restrict__ dblBC,
                                              const ushort* __restrict__ xcb,
                                              const ushort* __restrict__ xcwh,
                                              const float* __restrict__ alog,
                                              float* __restrict__ Pg,
                                              float* __restrict__ Hg) {
    __shared__ float sB[32][16];
    int lane = threadIdx.x;
    int d0 = blockIdx.x * 64, ch = blockIdx.y, kb = blockIdx.z;
    int k = kb & 3, b = kb >> 2;
    int d = d0 + lane;
    float A2[16];
    {
        const float4* ap = (const float4*)(alog + ((size_t)(k * 768 + d)) * 16);
#pragma unroll
        for (int q = 0; q < 4; ++q) {
            float4 v = ap[q];
            A2[4 * q + 0] = -__expf(v.x) * 1.44269504f;
            A2[4 * q + 1] = -__expf(v.y) * 1.44269504f;
            A2[4 * q + 2] = -__expf(v.z) * 1.44269504f;
            A2[4 * q + 3] = -__expf(v.w) * 1.44269504f;
        }
    }
    int l0 = ch * 32;
    const ushort* dts = dtscan + ((size_t)((k * 2 + b) * 1024 + l0)) * 768 + d;
    const ushort* ub = ((k & 1) ? xcwh : xcb) + (size_t)b * 786432 + d;
    const float* bcp = dblBC + (size_t)kb * 1024 * 32;
    float rdt[32], ru[32], rB[8];
#pragma unroll
    for (int i = 0; i < 32; ++i) rdt[i] = bf2f(dts[(size_t)i * 768]);
    if (k & 2) {
#pragma unroll
        for (int i = 0; i < 32; ++i)
            ru[i] = bf2f(ub[(size_t)(1023 - (l0 + i)) * 768]);
    } else {
#pragma unroll
        for (int i = 0; i < 32; ++i) ru[i] = bf2f(ub[(size_t)(l0 + i) * 768]);
    }
    int bi = lane >> 4, bn_ = lane & 15;
#pragma unroll
    for (int j = 0; j < 8; ++j)
        rB[j] = bcp[(size_t)(l0 + bi + 4 * j) * 32 + bn_];
#pragma unroll
    for (int j = 0; j < 8; ++j) sB[bi + 4 * j][bn_] = rB[j];
    __syncthreads();
    float h[16], P[16];
#pragma unroll
    for (int n = 0; n < 16; ++n) { h[n] = 0.f; P[n] = 1.f; }
#pragma unroll 4
    for (int i = 0; i < 32; ++i) {
        float dtv = rdt[i], dtu = dtv * ru[i];
        const float4* B4 = (const float4*)&sB[i][0];
        float4 q0 = B4[0], q1 = B4[1], q2 = B4[2], q3 = B4[3];
        float Bv[16] = {q0.x, q0.y, q0.z, q0.w, q1.x, q1.y, q1.z, q1.w,
                        q2.x, q2.y, q2.z, q2.w, q3.x, q3.y, q3.z, q3.w};
#pragma unroll
        for (int n = 0; n < 16; ++n) {
            float a = __builtin_amdgcn_exp2f(dtv * A2[n]);
            P[n] *= a;
            h[n] = a * h[n] + dtu * Bv[n];
        }
    }
    float* pp = Pg + ((size_t)(kb * 32 + ch)) * 12288 + d * 16;
    float* hp = Hg + ((size_t)(kb * 32 + ch)) * 12288 + d * 16;
#pragma unroll
    for (int q = 0; q < 4; ++q) {
        float4 pv = {P[4 * q], P[4 * q + 1], P[4 * q + 2], P[4 * q + 3]};
        float4 hv = {h[4 * q], h[4 * q + 1], h[4 * q + 2], h[4 * q + 3]};
        *(float4*)(pp + 4 * q) = pv;
        *(float4*)(hp + 4 * q) = hv;
    }
}

// prefix fold: h0[ch] for all chains. 8 kb * 12288 threads, unrolled over 31.
__global__ __launch_bounds__(256) void comb_k(const float* __restrict__ Pg,
                                              const float* __restrict__ Hg,
                                              float* __restrict__ H0g) {
    int t = blockIdx.x * 256 + threadIdx.x;   // 98304
    int kb = t / 12288, dn = t % 12288;
    size_t base = (size_t)kb * 32 * 12288 + dn;
    float pv[31], hv[31];
#pragma unroll
    for (int ch = 0; ch < 31; ++ch) {
        pv[ch] = Pg[base + (size_t)ch * 12288];
        hv[ch] = Hg[base + (size_t)ch * 12288];
    }
    float h = 0.f;
    H0g[base] = 0.f;
#pragma unroll
    for (int ch = 0; ch < 31; ++ch) {
        h = pv[ch] * h + hv[ch];
        H0g[base + (size_t)(ch + 1) * 12288] = h;
    }
}

__global__ __launch_bounds__(64) void scan_p2(const ushort* __restrict__ dtscan,
                                              const float* __restrict__ dblBC,
                                              const ushort* __restrict__ xcb,
                                              const ushort* __restrict__ xcwh,
                                              const float* __restrict__ alog,
                                              const float* __restrict__ H0g,
                                              ushort* __restrict__ y4b) {
    __shared__ float sB[32][16];
    __shared__ float sC[32][16];
    int lane = threadIdx.x;
    int d0 = blockIdx.x * 64, ch = blockIdx.y, kb = blockIdx.z;
    int k = kb & 3, b = kb >> 2;
    int d = d0 + lane;
    float A2[16];
    {
        const float4* ap = (const float4*)(alog + ((size_t)(k * 768 + d)) * 16);
#pragma unroll
        for (int q = 0; q < 4; ++q) {
            float4 v = ap[q];
            A2[4 * q + 0] = -__expf(v.x) * 1.44269504f;
            A2[4 * q + 1] = -__expf(v.y) * 1.44269504f;
            A2[4 * q + 2] = -__expf(v.z) * 1.44269504f;
            A2[4 * q + 3] = -__expf(v.w) * 1.44269504f;
        }
    }
    float h[16];
    {
        const float4* h0p =
            (const float4*)(H0g + ((size_t)(kb * 32 + ch)) * 12288 + d * 16);
#pragma unroll
        for (int q = 0; q < 4; ++q) {
            float4 hv = h0p[q];
            h[4 * q + 0] = hv.x; h[4 * q + 1] = hv.y;
            h[4 * q + 2] = hv.z; h[4 * q + 3] = hv.w;
        }
    }
    int l0 = ch * 32;
    const ushort* dts = dtscan + ((size_t)((k * 2 + b) * 1024 + l0)) * 768 + d;
    const ushort* ub = ((k & 1) ? xcwh : xcb) + (size_t)b * 786432 + d;
    const float* bcp = dblBC + (size_t)kb * 1024 * 32;
    ushort* yp = y4b + ((size_t)(kb * 1024 + l0)) * 768 + d;
    float rdt[32], ru[32], rB[8], rC[8];
#pragma unroll
    for (int i = 0; i < 32; ++i) rdt[i] = bf2f(dts[(size_t)i * 768]);
    if (k & 2) {
#pragma unroll
        for (int i = 0; i < 32; ++i)
            ru[i] = bf2f(ub[(size_t)(1023 - (l0 + i)) * 768]);
    } else {
#pragma unroll
        for (int i = 0; i < 32; ++i) ru[i] = bf2f(ub[(size_t)(l0 + i) * 768]);
    }
    int bi = lane >> 4, bn_ = lane & 15;
#pragma unroll
    for (int j = 0; j < 8; ++j) {
        rB[j] = bcp[(size_t)(l0 + bi + 4 * j) * 32 + bn_];
        rC[j] = bcp[(size_t)(l0 + bi + 4 * j) * 32 + 16 + bn_];
    }
#pragma unroll
    for (int j = 0; j < 8; ++j) {
        sB[bi + 4 * j][bn_] = rB[j];
        sC[bi + 4 * j][bn_] = rC[j];
    }
    __syncthreads();
#pragma unroll 4
    for (int i = 0; i < 32; ++i) {
        float dtv = rdt[i], dtu = dtv * ru[i];
        const float4* B4 = (const float4*)&sB[i][0];
        const float4* C4 = (const float4*)&sC[i][0];
        float4 q0 = B4[0], q1 = B4[1], q2 = B4[2], q3 = B4[3];
        float Bv[16] = {q0.x, q0.y, q0.z, q0.w, q1.x, q1.y, q1.z, q1.w,
                        q2.x, q2.y, q2.z, q2.w, q3.x, q3.y, q3.z, q3.w};
        float4 c0 = C4[0], c1 = C4[1], c2 = C4[2], c3 = C4[3];
        float Cv[16] = {c0.x, c0.y, c0.z, c0.w, c1.x, c1.y, c1.z, c1.w,
                        c2.x, c2.y, c2.z, c2.w, c3.x, c3.y, c3.z, c3.w};
        float y = 0.f;
#pragma unroll
        for (int n = 0; n < 16; ++n) {
            float a = __builtin_amdgcn_exp2f(dtv * A2[n]);
            h[n] = a * h[n] + dtu * Bv[n];
            y += h[n] * Cv[n];
        }
        yp[(size_t)i * 768] = f2bf(y);
    }
}

// ------- sum 4 dirs (row-gather from scan order) + D*u, out-LN, *silu(z) ---------
__global__ __launch_bounds__(256) void fuse_out_k(const ushort* __restrict__ y4b,
                                                  const ushort* __restrict__ xcb,
                                                  const ushort* __restrict__ xzb,
                                                  const float* __restrict__ ds,
                                                  const float* __restrict__ onw,
                                                  const float* __restrict__ onb,
                                                  ushort* __restrict__ g) {
    int w = threadIdx.x >> 6, lane = threadIdx.x & 63;
    int row = blockIdx.x * 4 + w;      // grid 512
    int b = row >> 10, p = row & 1023;
    int l0 = scan_pos(0, p), l1 = scan_pos(1, p);
    int l2 = scan_pos(2, p), l3 = scan_pos(3, p);
    const ushort* y0 = y4b + ((size_t)((b * 4 + 0) * 1024 + l0)) * 768;
    const ushort* y1 = y4b + ((size_t)((b * 4 + 1) * 1024 + l1)) * 768;
    const ushort* y2 = y4b + ((size_t)((b * 4 + 2) * 1024 + l2)) * 768;
    const ushort* y3 = y4b + ((size_t)((b * 4 + 3) * 1024 + l3)) * 768;
    float v[12], s1 = 0.f, s2 = 0.f;
#pragma unroll
    for (int q = 0; q < 12; ++q) {
        int d = lane + 64 * q;
        float u = bf2f(xcb[(size_t)row * 768 + d]);
        float dsum = ds[d] + ds[768 + d] + ds[1536 + d] + ds[2304 + d];
        float val = dsum * u + bf2f(y0[d]) + bf2f(y1[d]) + bf2f(y2[d]) + bf2f(y3[d]);
        v[q] = val; s1 += val; s2 += val * val;
    }
#pragma unroll
    for (int m = 1; m < 64; m <<= 1) {
        s1 += __shfl_xor(s1, m); s2 += __shfl_xor(s2, m);
    }
    float mean = s1 * (1.f / 768.f);
    float rstd = rsqrtf(s2 * (1.f / 768.f) - mean * mean + 1e-5f);
#pragma unroll
    for (int q = 0; q < 12; ++q) {
        int d = lane + 64 * q;
        float zz = bf2f(xzb[(size_t)row * 1536 + 768 + d]);
        float sil = zz * sigmoidf_(zz);
        g[(size_t)row * 768 + d] = f2bf(((v[q] - mean) * rstd * onw[d] + onb[d]) * sil);
    }
}

extern "C" void kernel_launch(void* const* d_in, const int* in_sizes, int n_in,
                              void* d_out, int out_size, void* d_ws, size_t ws_size,
                              hipStream_t stream) {
    const float* x    = (const float*)d_in[0];
    const float* skip = (const float*)d_in[1];
    const float* pew  = (const float*)d_in[2];
    const float* pnw  = (const float*)d_in[3];
    const float* pnb  = (const float*)d_in[4];
    const float* lpw  = (const float*)d_in[5];
    const float* lpb  = (const float*)d_in[6];
    const float* blw  = (const float*)d_in[7];
    const float* blb  = (const float*)d_in[8];
    const float* inw  = (const float*)d_in[9];
    const float* cw   = (const float*)d_in[10];
    const float* cb   = (const float*)d_in[11];
    const float* xpw  = (const float*)d_in[12];
    const float* dtw  = (const float*)d_in[13];
    const float* dtbi = (const float*)d_in[14];
    const float* alog = (const float*)d_in[15];
    const float* ds   = (const float*)d_in[16];
    const float* onw  = (const float*)d_in[17];
    const float* onb  = (const float*)d_in[18];
    const float* ow   = (const float*)d_in[19];
    float* out = (float*)d_out;

    char* base = (char*)d_ws;
    auto alloc = [&](size_t bytes) -> char* {
        char* p = base;
        base += (bytes + 255) & ~(size_t)255;
        return p;
    };
    float*  xh    = (float*)alloc(2048 * 384 * 4);
    ushort* hbuf  = (ushort*)alloc(2048 * 768 * 2);
    ushort* xzb   = (ushort*)alloc((size_t)2048 * 1536 * 2);
    ushort* xcb   = (ushort*)alloc(2048 * 768 * 2);
    ushort* xcwh  = (ushort*)alloc(2048 * 768 * 2);
    float*  dblBC = (float*)alloc(8192 * 32 * 4);
    ushort* dtrb  = (ushort*)alloc((size_t)4 * 2048 * 32 * 2);
    ushort* dtscan= (ushort*)alloc((size_t)4 * 2048 * 768 * 2);
    ushort* y4b   = (ushort*)alloc((size_t)8192 * 768 * 2);
    float*  Pg    = (float*)alloc((size_t)8 * 32 * 12288 * 4);
    float*  Hg    = (float*)alloc((size_t)8 * 32 * 12288 * 4);
    float*  H0g   = (float*)alloc((size_t)8 * 32 * 12288 * 4);
    ushort* xspe  = (ushort*)alloc(512 * 768 * 2);
    float*  t1    = (float*)alloc(512 * 1536 * 4);
    ushort* wpe   = (ushort*)alloc((size_t)1536 * 768 * 2);
    ushort* wlp   = (ushort*)alloc(384 * 768 * 2);
    ushort* winb  = (ushort*)alloc((size_t)2 * 1536 * 384 * 2);
    ushort* wob   = (ushort*)alloc((size_t)2 * 384 * 768 * 2);
    ushort* wxpp  = (ushort*)alloc((size_t)2 * 256 * 768 * 2);
    ushort* wdtp  = (ushort*)alloc((size_t)2 * 4 * 768 * 32 * 2);

    // weight conversion + x transpose (merged)
    cvt_all_k<<<4128, 256, 0, stream>>>(pew, lpw, inw, ow, xpw, dtw, x,
                                        wpe, wlp, winb, wob, wxpp, wdtp, xspe);

    // ---- Stage A ----
    gemm64<<<dim3(24, 8), 256, 0, stream>>>(xspe, wpe, nullptr, nullptr, t1,
                                            nullptr, nullptr, nullptr,
                                            512, 1536, 768, 0, 0, 0, 0, 0);
    peskip_k<<<1280, 256, 0, stream>>>(t1, pnw, pnb, skip, hbuf);
    gemm64<<<dim3(6, 32), 256, 0, stream>>>(hbuf, wlp, lpb, nullptr, xh,
                                            nullptr, nullptr, nullptr,
                                            2048, 384, 768, 0, 0, 0, 0, 0);

    // ---- 2 VSS blocks ----
    for (int blk = 0; blk < 2; ++blk) {
        const ushort* inw_i = winb + (size_t)blk * 1536 * 384;
        const float*  cw_i  = cw + (size_t)blk * 768 * 9;
        const float*  cb_i  = cb + (size_t)blk * 768;
        const ushort* xpw_i = wxpp + (size_t)blk * 256 * 768;
        const ushort* dtw_i = wdtp + (size_t)blk * 4 * 768 * 32;
        const float*  dtb_i = dtbi + (size_t)blk * 4 * 768;
        const float*  al_i  = alog + (size_t)blk * 4 * 768 * 16;
        const float*  ds_i  = ds + (size_t)blk * 4 * 768;
        const float*  onw_i = onw + (size_t)blk * 768;
        const float*  onb_i = onb + (size_t)blk * 768;
        const ushort* ow_i  = wob + (size_t)blk * 384 * 768;

        ln_rows_384<<<512, 256, 0, stream>>>(xh, blw + blk * 384, blb + blk * 384,
                                             hbuf);
        gemm64<<<dim3(24, 32), 256, 0, stream>>>(hbuf, inw_i, nullptr, nullptr,
                                                 nullptr, xzb, nullptr, nullptr,
                                                 2048, 1536, 384, 0, 0, 0, 0, 3);
        conv_silu_k<<<2048, 256, 0, stream>>>(xzb, cw_i, cb_i, xcb, xcwh);
        gemm64<<<dim3(4, 32), 256, 0, stream>>>(xcb, xpw_i, nullptr, nullptr,
                                                nullptr, nullptr, dblBC, dtrb,
                                                2048, 256, 768, 0, 0, 0, 0, 2);
        // A rows (dtrb) are scan-ordered -> output IS dtscan, contiguous stores
        gemm64<<<dim3(12, 32, 4), 256, 0, stream>>>(dtrb, dtw_i, dtb_i, nullptr,
                                                    nullptr, dtscan, nullptr,
                                                    nullptr, 2048, 768, 32,
                                                    2048 * 32, 768 * 32, 768,
                                                    (long)2048 * 768, 1);
        scan_p1<<<dim3(12, 31, 8), 64, 0, stream>>>(dtscan, dblBC, xcb, xcwh,
                                                    al_i, Pg, Hg);
        comb_k<<<384, 256, 0, stream>>>(Pg, Hg, H0g);
        scan_p2<<<dim3(12, 32, 8), 64, 0, stream>>>(dtscan, dblBC, xcb, xcwh,
                                                    al_i, H0g, y4b);
        fuse_out_k<<<512, 256, 0, stream>>>(y4b, xcb, xzb, ds_i, onw_i, onb_i,
                                            hbuf);
        gemm64<<<dim3(6, 32), 256, 0, stream>>>(hbuf, ow_i, nullptr, xh, xh,
                                                nullptr, nullptr, nullptr,
                                                2048, 384, 768, 0, 0, 0, 0, 0);
    }

    tr_out_k<<<dim3(32, 12, 2), 256, 0, stream>>>(xh, out);
}